// Round 16
// baseline (1933.049 us; speedup 1.0000x reference)
//
#include <hip/hip_runtime.h>

typedef unsigned short u16;
typedef unsigned int u32;
using short8 = __attribute__((ext_vector_type(8))) short;
using floatx4 = __attribute__((ext_vector_type(4))) float;

#define DMODEL 1024
#define DFF 4096
#define INNER 2048
#define DH 128
#define CTX 200
#define R_TOT 16000
#define ABN 40
#define AROWS (ABN * CTX)
#define AM (ABN * 8)
#define SCALE_Q 0.08838834764831845f

__device__ __forceinline__ u16 f2bf(float f) {
    union { float f; u32 u; } v; v.f = f;
    u32 r = v.u + 0x7FFFu + ((v.u >> 16) & 1u);
    return (u16)(r >> 16);
}
__device__ __forceinline__ float bf2f(u16 u) {
    union { u32 u; float f; } v; v.u = ((u32)u) << 16; return v.f;
}
__device__ __forceinline__ float sigmoidf_(float x) { return 1.f / (1.f + __expf(-x)); }

__device__ __forceinline__ void load_lds16(const void* g, void* l) {
    __builtin_amdgcn_global_load_lds((const __attribute__((address_space(1))) u32*)g,
                                     (__attribute__((address_space(3))) u32*)l, 16, 0, 0);
}

// XCD stripe-cluster remap: gx MUST be a multiple of 8 (pad blocks early-exit on row0>=M).
__device__ __forceinline__ void xcd_stripe_remap(int& bx, int& by) {
    const int gx = gridDim.x;
    const int gxs = gx >> 3;
    const int id = blockIdx.y * gx + blockIdx.x;
    const int xcd = id & 7;
    const int local = id >> 3;
    bx = xcd * gxs + (local % gxs);
    by = local / gxs;
}

// ====== k_g8: 256x256 tile, BK=64, 8 waves (2Mx4N), 8-phase counted-vmcnt pipeline ======
// K-SPLIT halves: buf = {Ak0,Ak1,Bk0,Bk1} planes of [256 rows][64B] (16KB each);
// phase q of tile t needs only 2 planes, so counted vmcnt(6) works (never drain mid-loop):
//   ph1: stage Ak0(t+1); vmcnt(6); bar; read bv(ks0)+av(mi0-3,ks0); lgkm0; 16 MFMA; bar
//   ph2: stage Bk0(t+1);           read av(mi4-7,ks0);              lgkm0; 16 MFMA; bar
//   ph3: stage Ak1(t+1); vmcnt(6); bar; read bv(ks1)+av(mi0-3,ks1); lgkm0; 16 MFMA; bar
//   ph4: stage Bk1(t+1);           read av(mi4-7,ks1);              lgkm0; 16 MFMA; bar
// FIFO retire: at ph1 the 6 newest outstanding = {Ak1(t),Bk1(t),Ak0(t+1)} so Ak0/Bk0(t)
// are retired; at ph3 the 6 newest = {Ak0,Bk0,Ak1}(t+1) so Ak1/Bk1(t) retired.
// Plane swizzle: byte col ^= ((row>>1)&3)<<4 (involution, conflict-free b128, 2-way max).
// MODE 0: bf16=alpha*v+bias ; 1: bf16=silu(v+bias) ; 2: f32=alpha*(v+bias)+resid ;
// MODE 3: paired GLU (even col=a-chan p, odd=gate-chan p) -> out[r][p]=a*sigmoid(gate).
template <int MODE>
__global__ __launch_bounds__(512, 1) void k_g8(const u16* __restrict__ A, int lda,
                                               const u16* __restrict__ Bt, int ldb,
                                               const float* __restrict__ bias, float alpha,
                                               void* out, int ldc, const float* resid, int M,
                                               int N, int K) {
    __shared__ __align__(128) char lds[131072];
    int bx, by;
    xcd_stripe_remap(bx, by);
    const int row0 = bx * 256, col0 = by * 256;
    if (row0 >= M) return;
    const int tid = threadIdx.x;
    const int lane = tid & 63;
    const int wave = tid >> 6;
    const int wrow = (wave >> 2) * 128;
    const int wcol = (wave & 3) * 64;
    const int lr = lane & 15;
    const int kg = lane >> 4;
    const int nt = K >> 6;

    // stage sources (2 chunks/thread per plane); khalf adds +64 bytes on source
    const char* pA[2];
    const char* pB[2];
    int so[2];
#pragma unroll
    for (int r = 0; r < 2; ++r) {
        int o = r * 8192 + tid * 16;
        int row = o >> 6;
        int col = (o & 63) ^ (((row >> 1) & 3) << 4);
        int ga = row0 + row;
        ga = (ga < M) ? ga : M - 1;
        int gb = col0 + row;
        gb = (gb < N) ? gb : N - 1;
        pA[r] = (const char*)A + (size_t)ga * ((size_t)lda * 2) + col;
        pB[r] = (const char*)Bt + (size_t)gb * ((size_t)ldb * 2) + col;
        so[r] = o;
    }
    // fragment read offsets within a plane
    int aoff[8], boff[4];
#pragma unroll
    for (int mi = 0; mi < 8; ++mi) {
        int row = wrow + mi * 16 + lr;
        aoff[mi] = row * 64 + ((kg * 16) ^ (((row >> 1) & 3) << 4));
    }
#pragma unroll
    for (int ni = 0; ni < 4; ++ni) {
        int row = wcol + ni * 16 + lr;
        boff[ni] = row * 64 + ((kg * 16) ^ (((row >> 1) & 3) << 4));
    }
    floatx4 acc[8][4];
#pragma unroll
    for (int i = 0; i < 8; ++i)
#pragma unroll
        for (int j = 0; j < 4; ++j) acc[i][j] = (floatx4){0.f, 0.f, 0.f, 0.f};

    // plane bases in buf: Ak0=0, Ak1=16K, Bk0=32K, Bk1=48K
#define STAGE_A(buf, kbyte, half)                                               \
    {                                                                           \
        load_lds16(pA[0] + (kbyte) + (half)*64, (buf) + (half)*16384 + so[0]);  \
        load_lds16(pA[1] + (kbyte) + (half)*64, (buf) + (half)*16384 + so[1]);  \
    }
#define STAGE_B(buf, kbyte, half)                                                       \
    {                                                                                   \
        load_lds16(pB[0] + (kbyte) + (half)*64, (buf) + 32768 + (half)*16384 + so[0]);  \
        load_lds16(pB[1] + (kbyte) + (half)*64, (buf) + 32768 + (half)*16384 + so[1]);  \
    }

    // prologue: tile 0, order Ak0,Bk0,Ak1,Bk1 (FIFO matches steady-state waits)
    STAGE_A(lds, 0, 0);
    STAGE_B(lds, 0, 0);
    STAGE_A(lds, 0, 1);
    STAGE_B(lds, 0, 1);

    for (int t = 0; t < nt; ++t) {
        char* cur = lds + (t & 1) * 65536;
        char* nxt = lds + ((t + 1) & 1) * 65536;
        const int kb = (t + 1) << 7;
        const bool pf = (t + 1 < nt);
        short8 av[4], bv[4];
        // ---- phase 1 ----
        if (pf) {
            STAGE_A(nxt, kb, 0);
            asm volatile("s_waitcnt vmcnt(6)" ::: "memory");
        } else {
            asm volatile("s_waitcnt vmcnt(4)" ::: "memory");
        }
        __builtin_amdgcn_s_barrier();
#pragma unroll
        for (int ni = 0; ni < 4; ++ni) bv[ni] = *(const short8*)(cur + 32768 + boff[ni]);
#pragma unroll
        for (int mi = 0; mi < 4; ++mi) av[mi] = *(const short8*)(cur + aoff[mi]);
        asm volatile("s_waitcnt lgkmcnt(0)" ::: "memory");
        __builtin_amdgcn_sched_barrier(0);
        __builtin_amdgcn_s_setprio(1);
#pragma unroll
        for (int mi = 0; mi < 4; ++mi)
#pragma unroll
            for (int ni = 0; ni < 4; ++ni)
                acc[mi][ni] =
                    __builtin_amdgcn_mfma_f32_16x16x32_bf16(av[mi], bv[ni], acc[mi][ni], 0, 0, 0);
        __builtin_amdgcn_s_setprio(0);
        __builtin_amdgcn_s_barrier();
        // ---- phase 2 ----
        if (pf) STAGE_B(nxt, kb, 0);
#pragma unroll
        for (int mi = 0; mi < 4; ++mi) av[mi] = *(const short8*)(cur + aoff[4 + mi]);
        asm volatile("s_waitcnt lgkmcnt(0)" ::: "memory");
        __builtin_amdgcn_sched_barrier(0);
        __builtin_amdgcn_s_setprio(1);
#pragma unroll
        for (int mi = 0; mi < 4; ++mi)
#pragma unroll
            for (int ni = 0; ni < 4; ++ni)
                acc[4 + mi][ni] =
                    __builtin_amdgcn_mfma_f32_16x16x32_bf16(av[mi], bv[ni], acc[4 + mi][ni], 0, 0, 0);
        __builtin_amdgcn_s_setprio(0);
        __builtin_amdgcn_s_barrier();
        // ---- phase 3 ----
        if (pf) {
            STAGE_A(nxt, kb, 1);
            asm volatile("s_waitcnt vmcnt(6)" ::: "memory");
        } else {
            asm volatile("s_waitcnt vmcnt(0)" ::: "memory");
        }
        __builtin_amdgcn_s_barrier();
#pragma unroll
        for (int ni = 0; ni < 4; ++ni) bv[ni] = *(const short8*)(cur + 49152 + boff[ni]);
#pragma unroll
        for (int mi = 0; mi < 4; ++mi) av[mi] = *(const short8*)(cur + 16384 + aoff[mi]);
        asm volatile("s_waitcnt lgkmcnt(0)" ::: "memory");
        __builtin_amdgcn_sched_barrier(0);
        __builtin_amdgcn_s_setprio(1);
#pragma unroll
        for (int mi = 0; mi < 4; ++mi)
#pragma unroll
            for (int ni = 0; ni < 4; ++ni)
                acc[mi][ni] =
                    __builtin_amdgcn_mfma_f32_16x16x32_bf16(av[mi], bv[ni], acc[mi][ni], 0, 0, 0);
        __builtin_amdgcn_s_setprio(0);
        __builtin_amdgcn_s_barrier();
        // ---- phase 4 ----
        if (pf) STAGE_B(nxt, kb, 1);
#pragma unroll
        for (int mi = 0; mi < 4; ++mi) av[mi] = *(const short8*)(cur + 16384 + aoff[4 + mi]);
        asm volatile("s_waitcnt lgkmcnt(0)" ::: "memory");
        __builtin_amdgcn_sched_barrier(0);
        __builtin_amdgcn_s_setprio(1);
#pragma unroll
        for (int mi = 0; mi < 4; ++mi)
#pragma unroll
            for (int ni = 0; ni < 4; ++ni)
                acc[4 + mi][ni] =
                    __builtin_amdgcn_mfma_f32_16x16x32_bf16(av[mi], bv[ni], acc[4 + mi][ni], 0, 0, 0);
        __builtin_amdgcn_s_setprio(0);
        __builtin_amdgcn_s_barrier();
    }
#undef STAGE_A
#undef STAGE_B
    u16* ob = (u16*)out;
    float* of = (float*)out;
#pragma unroll
    for (int mi = 0; mi < 8; ++mi)
#pragma unroll
        for (int ni = 0; ni < 4; ++ni)
#pragma unroll
            for (int rr = 0; rr < 4; ++rr) {
                const int r = row0 + wrow + mi * 16 + kg * 4 + rr;
                const int c = col0 + wcol + ni * 16 + lr;
                const float v = acc[mi][ni][rr];
                if (MODE == 3) {
                    float tt = v + ((c & 1) ? bias[2048 + (c >> 1)] : bias[c >> 1]);
                    float g = __shfl_xor(tt, 1);
                    if (!(c & 1) && r < M)
                        ob[(size_t)r * ldc + (c >> 1)] = f2bf(tt * sigmoidf_(g));
                } else {
                    if (r >= M) continue;
                    size_t idx = (size_t)r * ldc + c;
                    float bb = bias ? bias[c] : 0.f;
                    if (MODE == 0) {
                        ob[idx] = f2bf(alpha * v + bb);
                    } else if (MODE == 1) {
                        float tt = v + bb;
                        ob[idx] = f2bf(tt * sigmoidf_(tt));
                    } else {
                        of[idx] = alpha * (v + bb) + resid[idx];
                    }
                }
            }
}

// ====== attention-internal core: single-buffer 32KB, 2-barrier, 4 blocks/CU ======
template <typename RowMap>
__device__ __forceinline__ void stage_tile_s(const char* __restrict__ src, RowMap rowoff,
                                             int nrows, int row0, int k0b, char* tile) {
    const int lane = threadIdx.x & 63;
    const int wave = threadIdx.x >> 6;
#pragma unroll
    for (int r = 0; r < 4; ++r) {
        int o = r * 4096 + wave * 1024 + lane * 16;
        int row = o >> 7;
        int srcb = (o & 127) ^ ((row & 7) << 4);
        int grow = row0 + row;
        grow = (grow < nrows) ? grow : (nrows - 1);
        load_lds16(src + rowoff(grow) + k0b + srcb, tile + r * 4096 + wave * 1024);
    }
}

template <typename RMA, typename RMB, typename Epi>
__device__ __forceinline__ void gemm_core_s(const char* __restrict__ A, RMA rma, int a_rows,
                                            const char* __restrict__ B, RMB rmb, int b_rows,
                                            int K, int row0, int col0, char* lds, Epi epi) {
    const int lane = threadIdx.x & 63;
    const int wave = threadIdx.x >> 6;
    const int wrow = (wave >> 1) * 64;
    const int wcol = (wave & 1) * 64;
    const int lr = lane & 15;
    const int kg = lane >> 4;
    const int nt = K >> 6;

    floatx4 acc[4][4];
#pragma unroll
    for (int i = 0; i < 4; ++i)
#pragma unroll
        for (int j = 0; j < 4; ++j) acc[i][j] = (floatx4){0.f, 0.f, 0.f, 0.f};

    for (int t = 0; t < nt; ++t) {
        const int kb = t << 7;
        stage_tile_s(A, rma, a_rows, row0, kb, lds);
        stage_tile_s(B, rmb, b_rows, col0, kb, lds + 16384);
        asm volatile("s_waitcnt vmcnt(0)" ::: "memory");
        __builtin_amdgcn_s_barrier();
#pragma unroll
        for (int ks = 0; ks < 2; ++ks) {
            short8 av[4], bv[4];
#pragma unroll
            for (int mi = 0; mi < 4; ++mi) {
                int row = wrow + mi * 16 + lr;
                int cb = (ks * 64 + kg * 16) ^ ((row & 7) << 4);
                av[mi] = *(const short8*)(lds + row * 128 + cb);
            }
#pragma unroll
            for (int ni = 0; ni < 4; ++ni) {
                int row = wcol + ni * 16 + lr;
                int cb = (ks * 64 + kg * 16) ^ ((row & 7) << 4);
                bv[ni] = *(const short8*)(lds + 16384 + row * 128 + cb);
            }
#pragma unroll
            for (int mi = 0; mi < 4; ++mi)
#pragma unroll
                for (int ni = 0; ni < 4; ++ni)
                    acc[mi][ni] = __builtin_amdgcn_mfma_f32_16x16x32_bf16(av[mi], bv[ni],
                                                                          acc[mi][ni], 0, 0, 0);
        }
        asm volatile("s_waitcnt lgkmcnt(0)" ::: "memory");
        __builtin_amdgcn_s_barrier();
    }
#pragma unroll
    for (int mi = 0; mi < 4; ++mi)
#pragma unroll
        for (int ni = 0; ni < 4; ++ni)
#pragma unroll
            for (int rr = 0; rr < 4; ++rr)
                epi(row0 + wrow + mi * 16 + kg * 4 + rr, col0 + wcol + ni * 16 + lr,
                    acc[mi][ni][rr]);
}

// scores[z][i][j] = q_scaled[i].k[j]  (bf16, cols padded to 256), z = local bnh
__global__ __launch_bounds__(256, 4) void k_qk(const u16* __restrict__ q,
                                               const u16* __restrict__ kvc,
                                               u16* __restrict__ sc, int bn0) {
    __shared__ __align__(128) char lds[32768];
    const int z = blockIdx.z, bnl = z >> 3, h = z & 7;
    const char* A = (const char*)(q + ((size_t)(bn0 + bnl) * CTX) * DMODEL + h * DH);
    const char* B = (const char*)(kvc + ((size_t)bnl * CTX) * (2 * DMODEL) + h * DH);
    u16* out = sc + (size_t)z * CTX * 256;
    gemm_core_s(A, [](int r) { return (size_t)r * (DMODEL * 2); }, CTX, B,
                [](int r) { return (size_t)r * (4 * DMODEL); }, CTX, DH, blockIdx.x * 128,
                blockIdx.y * 128, lds, [&](int r, int c, float v) {
                    if (r < CTX) out[(size_t)r * 256 + c] = f2bf(v);
                });
}

// scores[m][i][j] += q'[m].rel[i][j]  (batched over i; A gathered from q via row map)
__global__ __launch_bounds__(256, 4) void k_pos(const u16* __restrict__ q,
                                                const u16* __restrict__ rel,
                                                u16* __restrict__ sc, int m0) {
    __shared__ __align__(128) char lds[32768];
    const int i = blockIdx.z;
    const char* B = (const char*)(rel + (size_t)i * CTX * DH);
    u16* out = sc + i * 256;
    gemm_core_s((const char*)q,
                [=](int r) {
                    int m = m0 + r;
                    return (size_t)(((m >> 3) * CTX + i) * DMODEL + (m & 7) * DH) * 2;
                },
                AM, B, [](int r) { return (size_t)r * (DH * 2); }, CTX, DH, blockIdx.x * 128,
                blockIdx.y * 128, lds, [&](int r, int c, float v) {
                    if (r < AM) {
                        size_t idx = (size_t)r * (CTX * 256) + c;
                        out[idx] = f2bf(bf2f(out[idx]) + v);
                    }
                });
}

// attn_out[(bn0+z/8)*CTX+i][(z&7)*DH+dh] = P[z][i][:].vT[z][dh][:]  (K=256 padded)
__global__ __launch_bounds__(256, 4) void k_pv(const u16* __restrict__ P,
                                               const u16* __restrict__ vT,
                                               u16* __restrict__ attn, int bn0) {
    __shared__ __align__(128) char lds[32768];
    const int z = blockIdx.z;
    u16* out = attn + ((size_t)(bn0 + (z >> 3)) * CTX) * DMODEL + (z & 7) * DH;
    const char* A = (const char*)(P + (size_t)z * CTX * 256);
    const char* B = (const char*)(vT + (size_t)z * DH * 256);
    gemm_core_s(A, [](int r) { return (size_t)r * 512; }, CTX, B,
                [](int r) { return (size_t)r * 512; }, DH, 256, blockIdx.x * 128, 0, lds,
                [&](int r, int c, float v) {
                    if (r < CTX) out[(size_t)r * DMODEL + c] = f2bf(v);
                });
}

// ---------------- LayerNorm ----------------
template <bool OUTF32>
__global__ __launch_bounds__(256) void k_ln(const float* __restrict__ x,
                                            const float* __restrict__ g,
                                            const float* __restrict__ b, void* __restrict__ out) {
    const int row = blockIdx.x, t = threadIdx.x, lane = t & 63, wv = t >> 6;
    const float4 v = ((const float4*)(x + (size_t)row * DMODEL))[t];
    float s = v.x + v.y + v.z + v.w;
    float q = v.x * v.x + v.y * v.y + v.z * v.z + v.w * v.w;
#pragma unroll
    for (int off = 32; off > 0; off >>= 1) { s += __shfl_down(s, off); q += __shfl_down(q, off); }
    __shared__ float rs_[4], rq_[4];
    if (lane == 0) { rs_[wv] = s; rq_[wv] = q; }
    __syncthreads();
    s = rs_[0] + rs_[1] + rs_[2] + rs_[3];
    q = rq_[0] + rq_[1] + rq_[2] + rq_[3];
    const float mu = s * (1.f / DMODEL);
    const float rstd = rsqrtf(q * (1.f / DMODEL) - mu * mu + 1e-5f);
    const float4 gv = ((const float4*)g)[t];
    const float4 bv = ((const float4*)b)[t];
    float o0 = (v.x - mu) * rstd * gv.x + bv.x;
    float o1 = (v.y - mu) * rstd * gv.y + bv.y;
    float o2 = (v.z - mu) * rstd * gv.z + bv.z;
    float o3 = (v.w - mu) * rstd * gv.w + bv.w;
    if (OUTF32) {
        ((float4*)out)[(size_t)row * 256 + t] = make_float4(o0, o1, o2, o3);
    } else {
        ushort4 r4;
        r4.x = f2bf(o0); r4.y = f2bf(o1); r4.z = f2bf(o2); r4.w = f2bf(o3);
        ((ushort4*)out)[(size_t)row * 256 + t] = r4;
    }
}

// softmax over j, in-place on bf16 scores; zeroes pad cols [CTX,256)
__global__ __launch_bounds__(256) void k_softmax(u16* __restrict__ sc) {
    const size_t row = blockIdx.x;
    const int t = threadIdx.x, lane = t & 63, wv = t >> 6;
    float v = (t < CTX) ? bf2f(sc[row * 256 + t]) : -3.0e38f;
    float m = v;
#pragma unroll
    for (int off = 32; off > 0; off >>= 1) m = fmaxf(m, __shfl_down(m, off));
    __shared__ float rm[4], rsum[4];
    if (lane == 0) rm[wv] = m;
    __syncthreads();
    m = fmaxf(fmaxf(rm[0], rm[1]), fmaxf(rm[2], rm[3]));
    float e = (t < CTX) ? __expf(v - m) : 0.f;
    float s = e;
#pragma unroll
    for (int off = 32; off > 0; off >>= 1) s += __shfl_down(s, off);
    if (lane == 0) rsum[wv] = s;
    __syncthreads();
    s = rsum[0] + rsum[1] + rsum[2] + rsum[3];
    sc[row * 256 + t] = f2bf(e / s);
}

// depthwise conv(K=15,pad=7)+BN(eval)+silu ; dense [8][2000][2048] in/out
__global__ __launch_bounds__(256) void k_dwconv(const u16* __restrict__ in,
                                                const float* __restrict__ w,
                                                const float* __restrict__ bng,
                                                const float* __restrict__ bnb,
                                                const float* __restrict__ bnm,
                                                const float* __restrict__ bnv,
                                                u16* __restrict__ out) {
    const int b = blockIdx.z, lt = blockIdx.x, cg = blockIdx.y;
    const int c = cg * 256 + threadIdx.x;  // 0..2047
    const int l0 = lt * 16;
    __shared__ u16 s[30][256];
#pragma unroll
    for (int rr = 0; rr < 30; ++rr) {
        int l = l0 + rr - 7;
        u16 v = 0;
        if (l >= 0 && l < 2000) v = in[((size_t)b * 2000 + l) * 2048 + c];
        s[rr][threadIdx.x] = v;
    }
    __syncthreads();
    float wv[15];
#pragma unroll
    for (int k = 0; k < 15; ++k) wv[k] = w[c * 15 + k];
    const float sc = rsqrtf(bnv[c] + 1e-5f) * bng[c];
    const float mean = bnm[c], bb = bnb[c];
#pragma unroll
    for (int l = 0; l < 16; ++l) {
        float acc = 0.f;
#pragma unroll
        for (int k = 0; k < 15; ++k) acc += bf2f(s[l + k][threadIdx.x]) * wv[k];
        float h = (acc - mean) * sc + bb;
        h = h * sigmoidf_(h);
        out[((size_t)b * 2000 + l0 + l) * 2048 + c] = f2bf(h);
    }
}

// weight transpose f32[K,N] -> bf16[N,K]; PAIR: row n -> (n<2048 ? 2n : 2(n-2048)+1)
template <bool PAIR>
__global__ __launch_bounds__(256) void k_wt(const float* __restrict__ w, u16* __restrict__ wt,
                                            int K, int N) {
    __shared__ float tile[32][33];
    const int k0 = blockIdx.x * 32, n0 = blockIdx.y * 32;
    const int tx = threadIdx.x & 31, ty = threadIdx.x >> 5;
#pragma unroll
    for (int i = 0; i < 32; i += 8) tile[ty + i][tx] = w[(size_t)(k0 + ty + i) * N + n0 + tx];
    __syncthreads();
#pragma unroll
    for (int i = 0; i < 32; i += 8) {
        int n = n0 + ty + i;
        int pn = PAIR ? ((n < 2048) ? 2 * n : 2 * (n - 2048) + 1) : n;
        wt[(size_t)pn * K + k0 + tx] = f2bf(tile[tx][ty + i]);
    }
}

// rel_bf16[i][j][dh] = bf16(rel_emb[dist[i][j]][dh])
__global__ void k_rel(const float* __restrict__ emb, const int* __restrict__ dist,
                      u16* __restrict__ rel) {
    const int bid = blockIdx.x;
    const int d = dist[bid];
    rel[(size_t)bid * DH + threadIdx.x] = f2bf(emb[(size_t)d * DH + threadIdx.x]);
}

// vT[z][dh][j] = v_chunk[bnl*CTX+j][DMODEL + h*DH + dh], zero-padded j in [CTX,256)
__global__ __launch_bounds__(256) void k_vt(const u16* __restrict__ kvc, u16* __restrict__ vT) {
    __shared__ u16 t_[64 * 130];
    const int z = blockIdx.x, jt = blockIdx.y;
    const int bnl = z >> 3, h = z & 7;
    const int j0 = jt * 64;
    for (int idx = threadIdx.x; idx < 8192; idx += 256) {
        int j = idx >> 7, dh = idx & 127;
        int jj = j0 + j;
        u16 val = 0;
        if (jj < CTX) val = kvc[((size_t)(bnl * CTX + jj)) * (2 * DMODEL) + DMODEL + h * DH + dh];
        t_[j * 130 + dh] = val;
    }
    __syncthreads();
    for (int idx = threadIdx.x; idx < 8192; idx += 256) {
        int dh = idx >> 6, j = idx & 63;
        vT[((size_t)z * DH + dh) * 256 + j0 + j] = t_[j * 130 + dh];
    }
}

__global__ void k_fill(float* o, int n, float v) {
    int i = blockIdx.x * 256 + threadIdx.x;
    if (i < n) o[i] = v;
}

extern "C" void kernel_launch(void* const* d_in, const int* in_sizes, int n_in, void* d_out,
                              int out_size, void* d_ws, size_t ws_size, hipStream_t stream) {
    const float* x_in = (const float*)d_in[0];
    const int* dists = (const int*)d_in[1];
    const float* ff1_ln_g = (const float*)d_in[2];
    const float* ff1_ln_b = (const float*)d_in[3];
    const float* ff1_up_w = (const float*)d_in[4];
    const float* ff1_up_b = (const float*)d_in[5];
    const float* ff1_down_w = (const float*)d_in[6];
    const float* ff1_down_b = (const float*)d_in[7];
    const float* attn_ln_g = (const float*)d_in[8];
    const float* attn_ln_b = (const float*)d_in[9];
    const float* wq = (const float*)d_in[10];
    const float* wkv = (const float*)d_in[11];
    const float* wo = (const float*)d_in[12];
    const float* wo_b = (const float*)d_in[13];
    const float* rel_emb = (const float*)d_in[14];
    const float* conv_ln_g = (const float*)d_in[15];
    const float* conv_ln_b = (const float*)d_in[16];
    const float* conv_up_w = (const float*)d_in[17];
    const float* conv_up_b = (const float*)d_in[18];
    const float* dw_w = (const float*)d_in[19];
    const float* bn_g = (const float*)d_in[20];
    const float* bn_b = (const float*)d_in[21];
    const float* bn_mean = (const float*)d_in[22];
    const float* bn_var = (const float*)d_in[23];
    const float* conv_down_w = (const float*)d_in[24];
    const float* conv_down_b = (const float*)d_in[25];
    const float* ff2_ln_g = (const float*)d_in[26];
    const float* ff2_ln_b = (const float*)d_in[27];
    const float* ff2_up_w = (const float*)d_in[28];
    const float* ff2_up_b = (const float*)d_in[29];
    const float* ff2_down_w = (const float*)d_in[30];
    const float* ff2_down_b = (const float*)d_in[31];
    const float* post_ln_g = (const float*)d_in[32];
    const float* post_ln_b = (const float*)d_in[33];

    char* W = (char*)d_ws;
    size_t off = 0;
    auto alloc = [&](size_t bytes) {
        char* p = W + off;
        off += (bytes + 255) & ~(size_t)255;
        return (u16*)p;
    };
    u16* slot = alloc((size_t)4096 * 1024 * 2);
    u16* ln_buf = alloc((size_t)R_TOT * DMODEL * 2);
    u16* arena = alloc((size_t)R_TOT * DFF * 2);
    u16* mid = arena;
    u16* rel_bf = arena;
    u16* bufA = rel_bf + (size_t)CTX * CTX * DH;
    u16* bufB = bufA + (size_t)AROWS * 2 * DMODEL;
    u16* smid = bufB + (size_t)R_TOT * DMODEL;
    u16* vT = smid + (size_t)AM * CTX * 256;
    u16* gluo = arena;                           // conv: [16000][2048]
    u16* convo = arena + (size_t)R_TOT * INNER;  // conv: [16000][2048]
    float* xs = (float*)d_out;

    if (ws_size < off) {
        k_fill<<<(out_size + 255) / 256, 256, 0, stream>>>((float*)d_out, out_size, 31337.f);
        return;
    }

    auto WT = [&](const float* s, int K, int N) {
        k_wt<false><<<dim3(K / 32, N / 32), 256, 0, stream>>>(s, slot, K, N);
    };

    const dim3 gUP(64, 16);  // 256^2: M=16000(->64 tiles padded), N=4096
    const dim3 gSQ(64, 4);   // M=16000, N=1024
    const dim3 gKV(32, 8);   // M=8000,  N=2048

    auto ff_block = [&](const float* lng, const float* lnb, const float* upw, const float* upb,
                        const float* dnw, const float* dnb, const float* resid,
                        const float* xsrc) {
        k_ln<false><<<R_TOT, 256, 0, stream>>>(xsrc, lng, lnb, ln_buf);
        WT(upw, 1024, 4096);
        k_g8<1><<<gUP, 512, 0, stream>>>(ln_buf, DMODEL, slot, DMODEL, upb, 1.f, mid, DFF,
                                         nullptr, R_TOT, DFF, DMODEL);
        WT(dnw, 4096, 1024);
        k_g8<2><<<gSQ, 512, 0, stream>>>(mid, DFF, slot, DFF, dnb, 0.5f, xs, DMODEL, resid,
                                         R_TOT, DMODEL, DFF);
    };

    // ---- FF1 ----
    ff_block(ff1_ln_g, ff1_ln_b, ff1_up_w, ff1_up_b, ff1_down_w, ff1_down_b, x_in, x_in);

    // ---- Attention ----
    k_ln<false><<<R_TOT, 256, 0, stream>>>(xs, attn_ln_g, attn_ln_b, ln_buf);
    k_rel<<<CTX * CTX, 128, 0, stream>>>(rel_emb, dists, rel_bf);
    WT(wq, 1024, 1024);
    k_g8<0><<<gSQ, 512, 0, stream>>>(ln_buf, DMODEL, slot, DMODEL, nullptr, SCALE_Q, bufB,
                                     DMODEL, nullptr, R_TOT, DMODEL, DMODEL);
    WT(wkv, 1024, 2048);
    for (int h = 0; h < 2; ++h) {
        const int bn0 = h * ABN, m0 = bn0 * 8;
        const u16* lnc = ln_buf + (size_t)bn0 * CTX * DMODEL;
        k_g8<0><<<gKV, 512, 0, stream>>>(lnc, DMODEL, slot, DMODEL, nullptr, 1.f, bufA,
                                         2 * DMODEL, nullptr, AROWS, 2 * DMODEL, DMODEL);
        k_vt<<<dim3(AM, 4), 256, 0, stream>>>(bufA, vT);
        k_qk<<<dim3(2, 2, AM), 256, 0, stream>>>(bufB, bufA, smid, bn0);
        k_pos<<<dim3(3, 2, CTX), 256, 0, stream>>>(bufB, rel_bf, smid, m0);
        k_softmax<<<AM * CTX, 256, 0, stream>>>(smid);
        k_pv<<<dim3(2, 1, AM), 256, 0, stream>>>(smid, vT, bufB, bn0);
    }
    WT(wo, 1024, 1024);
    k_g8<2><<<gSQ, 512, 0, stream>>>(bufB, DMODEL, slot, DMODEL, wo_b, 1.f, xs, DMODEL, xs,
                                     R_TOT, DMODEL, DMODEL);

    // ---- Conv module: fused up+GLU (paired weights) -> dwconv -> down ----
    k_ln<false><<<R_TOT, 256, 0, stream>>>(xs, conv_ln_g, conv_ln_b, ln_buf);
    k_wt<true><<<dim3(1024 / 32, 4096 / 32), 256, 0, stream>>>(conv_up_w, slot, 1024, 4096);
    k_g8<3><<<gUP, 512, 0, stream>>>(ln_buf, DMODEL, slot, DMODEL, conv_up_b, 1.f, gluo, INNER,
                                     nullptr, R_TOT, DFF, DMODEL);
    k_dwconv<<<dim3(125, 8, 8), 256, 0, stream>>>(gluo, dw_w, bn_g, bn_b, bn_mean, bn_var,
                                                  convo);
    WT(conv_down_w, 2048, 1024);
    k_g8<2><<<gSQ, 512, 0, stream>>>(convo, INNER, slot, INNER, conv_down_b, 1.f, xs, DMODEL,
                                     xs, R_TOT, DMODEL, INNER);

    // ---- FF2 ----
    ff_block(ff2_ln_g, ff2_ln_b, ff2_up_w, ff2_up_b, ff2_down_w, ff2_down_b, xs, xs);

    // ---- final LayerNorm (in-place on d_out) ----
    k_ln<true><<<R_TOT, 256, 0, stream>>>(xs, post_ln_g, post_ln_b, d_out);
}

// Round 17
// 1679.704 us; speedup vs baseline: 1.1508x; 1.1508x over previous
//
#include <hip/hip_runtime.h>

typedef unsigned short u16;
typedef unsigned int u32;
using short8 = __attribute__((ext_vector_type(8))) short;
using floatx4 = __attribute__((ext_vector_type(4))) float;

#define DMODEL 1024
#define DFF 4096
#define INNER 2048
#define DH 128
#define CTX 200
#define R_TOT 16000
#define ABN 40
#define AROWS (ABN * CTX)
#define AM (ABN * 8)
#define SCALE_Q 0.08838834764831845f

__device__ __forceinline__ u16 f2bf(float f) {
    union { float f; u32 u; } v; v.f = f;
    u32 r = v.u + 0x7FFFu + ((v.u >> 16) & 1u);
    return (u16)(r >> 16);
}
__device__ __forceinline__ float bf2f(u16 u) {
    union { u32 u; float f; } v; v.u = ((u32)u) << 16; return v.f;
}
__device__ __forceinline__ float sigmoidf_(float x) { return 1.f / (1.f + __expf(-x)); }

__device__ __forceinline__ void load_lds16(const void* g, void* l) {
    __builtin_amdgcn_global_load_lds((const __attribute__((address_space(1))) u32*)g,
                                     (__attribute__((address_space(3))) u32*)l, 16, 0, 0);
}

// XCD stripe-cluster remap: gx MUST be a multiple of 8 (pad blocks early-exit on row0>=M).
__device__ __forceinline__ void xcd_stripe_remap(int& bx, int& by) {
    const int gx = gridDim.x;
    const int gxs = gx >> 3;
    const int id = blockIdx.y * gx + blockIdx.x;
    const int xcd = id & 7;
    const int local = id >> 3;
    bx = xcd * gxs + (local % gxs);
    by = local / gxs;
}

// epilogue: MODE 0 bf16=alpha*v+bias ; 1 bf16=silu(v+bias) ; 2 f32=alpha*(v+bias)+resid
template <int MODE>
__device__ __forceinline__ void epi_store(int r, int c, float v, int M, int ldc,
                                          const float* bias, float alpha, void* out,
                                          const float* resid) {
    if (r >= M) return;
    size_t idx = (size_t)r * ldc + c;
    float bb = bias ? bias[c] : 0.f;
    if (MODE == 0) {
        ((u16*)out)[idx] = f2bf(alpha * v + bb);
    } else if (MODE == 1) {
        float t = v + bb;
        ((u16*)out)[idx] = f2bf(t * sigmoidf_(t));
    } else {
        ((float*)out)[idx] = alpha * (v + bb) + resid[idx];
    }
}

// ====== k_g: 128x128, 4 waves, 32KB single-buffer, 2-barrier, 4 blocks/CU ======
// Co-residency (m114 implicit cross-block overlap) is the verified lever: another
// block's MFMA hides this block's vmcnt(0)+barrier drain. 60 VGPR + 64 AGPR = 124
// <= 2048/16 -> no spill at 16 waves/CU; LDS 4x32KB = 128 <= 160KB.
template <int MODE>
__global__ __launch_bounds__(256, 4) void k_g(const u16* __restrict__ A, int lda,
                                              const u16* __restrict__ Bt, int ldb,
                                              const float* __restrict__ bias, float alpha,
                                              void* out, int ldc, const float* resid, int M,
                                              int N, int K) {
    __shared__ __align__(128) char lds[32768];
    int bx, by;
    xcd_stripe_remap(bx, by);
    const int row0 = bx * 128, col0 = by * 128;
    if (row0 >= M) return;
    const int lane = threadIdx.x & 63;
    const int wave = threadIdx.x >> 6;
    const int wrow = (wave >> 1) * 64;
    const int wcol = (wave & 1) * 64;
    const int lr = lane & 15;
    const int kg = lane >> 4;
    const int nt = K >> 6;

    const char* sA[4];
    const char* sB[4];
#pragma unroll
    for (int r = 0; r < 4; ++r) {
        int o = r * 4096 + wave * 1024 + lane * 16;
        int row = o >> 7;
        int srcb = (o & 127) ^ ((row & 7) << 4);
        int ga = row0 + row;
        ga = (ga < M) ? ga : M - 1;
        sA[r] = (const char*)A + (size_t)ga * ((size_t)lda * 2) + srcb;
        int gb = col0 + row;
        gb = (gb < N) ? gb : N - 1;
        sB[r] = (const char*)Bt + (size_t)gb * ((size_t)ldb * 2) + srcb;
    }
    floatx4 acc[4][4];
#pragma unroll
    for (int i = 0; i < 4; ++i)
#pragma unroll
        for (int j = 0; j < 4; ++j) acc[i][j] = (floatx4){0.f, 0.f, 0.f, 0.f};

    for (int t = 0; t < nt; ++t) {
        const int kb = t << 7;
#pragma unroll
        for (int r = 0; r < 4; ++r) {
            load_lds16(sA[r] + kb, lds + r * 4096 + wave * 1024);
            load_lds16(sB[r] + kb, lds + 16384 + r * 4096 + wave * 1024);
        }
        asm volatile("s_waitcnt vmcnt(0)" ::: "memory");
        __builtin_amdgcn_s_barrier();
#pragma unroll
        for (int ks = 0; ks < 2; ++ks) {
            short8 av[4], bv[4];
#pragma unroll
            for (int mi = 0; mi < 4; ++mi) {
                int row = wrow + mi * 16 + lr;
                int cb = (ks * 64 + kg * 16) ^ ((row & 7) << 4);
                av[mi] = *(const short8*)(lds + row * 128 + cb);
            }
#pragma unroll
            for (int ni = 0; ni < 4; ++ni) {
                int row = wcol + ni * 16 + lr;
                int cb = (ks * 64 + kg * 16) ^ ((row & 7) << 4);
                bv[ni] = *(const short8*)(lds + 16384 + row * 128 + cb);
            }
#pragma unroll
            for (int mi = 0; mi < 4; ++mi)
#pragma unroll
                for (int ni = 0; ni < 4; ++ni)
                    acc[mi][ni] = __builtin_amdgcn_mfma_f32_16x16x32_bf16(av[mi], bv[ni],
                                                                          acc[mi][ni], 0, 0, 0);
        }
        asm volatile("s_waitcnt lgkmcnt(0)" ::: "memory");
        __builtin_amdgcn_s_barrier();
    }
#pragma unroll
    for (int mi = 0; mi < 4; ++mi)
#pragma unroll
        for (int ni = 0; ni < 4; ++ni)
#pragma unroll
            for (int rr = 0; rr < 4; ++rr)
                epi_store<MODE>(row0 + wrow + mi * 16 + kg * 4 + rr, col0 + wcol + ni * 16 + lr,
                                acc[mi][ni][rr], M, ldc, bias, alpha, out, resid);
}

// ====== attention-internal core: single-buffer 32KB, 2-barrier, 4 blocks/CU ======
template <typename RowMap>
__device__ __forceinline__ void stage_tile_s(const char* __restrict__ src, RowMap rowoff,
                                             int nrows, int row0, int k0b, char* tile) {
    const int lane = threadIdx.x & 63;
    const int wave = threadIdx.x >> 6;
#pragma unroll
    for (int r = 0; r < 4; ++r) {
        int o = r * 4096 + wave * 1024 + lane * 16;
        int row = o >> 7;
        int srcb = (o & 127) ^ ((row & 7) << 4);
        int grow = row0 + row;
        grow = (grow < nrows) ? grow : (nrows - 1);
        load_lds16(src + rowoff(grow) + k0b + srcb, tile + r * 4096 + wave * 1024);
    }
}

template <typename RMA, typename RMB, typename Epi>
__device__ __forceinline__ void gemm_core_s(const char* __restrict__ A, RMA rma, int a_rows,
                                            const char* __restrict__ B, RMB rmb, int b_rows,
                                            int K, int row0, int col0, char* lds, Epi epi) {
    const int lane = threadIdx.x & 63;
    const int wave = threadIdx.x >> 6;
    const int wrow = (wave >> 1) * 64;
    const int wcol = (wave & 1) * 64;
    const int lr = lane & 15;
    const int kg = lane >> 4;
    const int nt = K >> 6;

    floatx4 acc[4][4];
#pragma unroll
    for (int i = 0; i < 4; ++i)
#pragma unroll
        for (int j = 0; j < 4; ++j) acc[i][j] = (floatx4){0.f, 0.f, 0.f, 0.f};

    for (int t = 0; t < nt; ++t) {
        const int kb = t << 7;
        stage_tile_s(A, rma, a_rows, row0, kb, lds);
        stage_tile_s(B, rmb, b_rows, col0, kb, lds + 16384);
        asm volatile("s_waitcnt vmcnt(0)" ::: "memory");
        __builtin_amdgcn_s_barrier();
#pragma unroll
        for (int ks = 0; ks < 2; ++ks) {
            short8 av[4], bv[4];
#pragma unroll
            for (int mi = 0; mi < 4; ++mi) {
                int row = wrow + mi * 16 + lr;
                int cb = (ks * 64 + kg * 16) ^ ((row & 7) << 4);
                av[mi] = *(const short8*)(lds + row * 128 + cb);
            }
#pragma unroll
            for (int ni = 0; ni < 4; ++ni) {
                int row = wcol + ni * 16 + lr;
                int cb = (ks * 64 + kg * 16) ^ ((row & 7) << 4);
                bv[ni] = *(const short8*)(lds + 16384 + row * 128 + cb);
            }
#pragma unroll
            for (int mi = 0; mi < 4; ++mi)
#pragma unroll
                for (int ni = 0; ni < 4; ++ni)
                    acc[mi][ni] = __builtin_amdgcn_mfma_f32_16x16x32_bf16(av[mi], bv[ni],
                                                                          acc[mi][ni], 0, 0, 0);
        }
        asm volatile("s_waitcnt lgkmcnt(0)" ::: "memory");
        __builtin_amdgcn_s_barrier();
    }
#pragma unroll
    for (int mi = 0; mi < 4; ++mi)
#pragma unroll
        for (int ni = 0; ni < 4; ++ni)
#pragma unroll
            for (int rr = 0; rr < 4; ++rr)
                epi(row0 + wrow + mi * 16 + kg * 4 + rr, col0 + wcol + ni * 16 + lr,
                    acc[mi][ni][rr]);
}

// scores[z][i][j] = q_scaled[i].k[j]  (bf16, cols padded to 256), z = local bnh
__global__ __launch_bounds__(256, 4) void k_qk(const u16* __restrict__ q,
                                               const u16* __restrict__ kvc,
                                               u16* __restrict__ sc, int bn0) {
    __shared__ __align__(128) char lds[32768];
    const int z = blockIdx.z, bnl = z >> 3, h = z & 7;
    const char* A = (const char*)(q + ((size_t)(bn0 + bnl) * CTX) * DMODEL + h * DH);
    const char* B = (const char*)(kvc + ((size_t)bnl * CTX) * (2 * DMODEL) + h * DH);
    u16* out = sc + (size_t)z * CTX * 256;
    gemm_core_s(A, [](int r) { return (size_t)r * (DMODEL * 2); }, CTX, B,
                [](int r) { return (size_t)r * (4 * DMODEL); }, CTX, DH, blockIdx.x * 128,
                blockIdx.y * 128, lds, [&](int r, int c, float v) {
                    if (r < CTX) out[(size_t)r * 256 + c] = f2bf(v);
                });
}

// scores[m][i][j] += q'[m].rel[i][j]  (batched over i; A gathered from q via row map)
__global__ __launch_bounds__(256, 4) void k_pos(const u16* __restrict__ q,
                                                const u16* __restrict__ rel,
                                                u16* __restrict__ sc, int m0) {
    __shared__ __align__(128) char lds[32768];
    const int i = blockIdx.z;
    const char* B = (const char*)(rel + (size_t)i * CTX * DH);
    u16* out = sc + i * 256;
    gemm_core_s((const char*)q,
                [=](int r) {
                    int m = m0 + r;
                    return (size_t)(((m >> 3) * CTX + i) * DMODEL + (m & 7) * DH) * 2;
                },
                AM, B, [](int r) { return (size_t)r * (DH * 2); }, CTX, DH, blockIdx.x * 128,
                blockIdx.y * 128, lds, [&](int r, int c, float v) {
                    if (r < AM) {
                        size_t idx = (size_t)r * (CTX * 256) + c;
                        out[idx] = f2bf(bf2f(out[idx]) + v);
                    }
                });
}

// attn_out[(bn0+z/8)*CTX+i][(z&7)*DH+dh] = P[z][i][:].vT[z][dh][:]  (K=256 padded)
__global__ __launch_bounds__(256, 4) void k_pv(const u16* __restrict__ P,
                                               const u16* __restrict__ vT,
                                               u16* __restrict__ attn, int bn0) {
    __shared__ __align__(128) char lds[32768];
    const int z = blockIdx.z;
    u16* out = attn + ((size_t)(bn0 + (z >> 3)) * CTX) * DMODEL + (z & 7) * DH;
    const char* A = (const char*)(P + (size_t)z * CTX * 256);
    const char* B = (const char*)(vT + (size_t)z * DH * 256);
    gemm_core_s(A, [](int r) { return (size_t)r * 512; }, CTX, B,
                [](int r) { return (size_t)r * 512; }, DH, 256, blockIdx.x * 128, 0, lds,
                [&](int r, int c, float v) {
                    if (r < CTX) out[(size_t)r * DMODEL + c] = f2bf(v);
                });
}

// ---------------- LayerNorm ----------------
template <bool OUTF32>
__global__ __launch_bounds__(256) void k_ln(const float* __restrict__ x,
                                            const float* __restrict__ g,
                                            const float* __restrict__ b, void* __restrict__ out) {
    const int row = blockIdx.x, t = threadIdx.x, lane = t & 63, wv = t >> 6;
    const float4 v = ((const float4*)(x + (size_t)row * DMODEL))[t];
    float s = v.x + v.y + v.z + v.w;
    float q = v.x * v.x + v.y * v.y + v.z * v.z + v.w * v.w;
#pragma unroll
    for (int off = 32; off > 0; off >>= 1) { s += __shfl_down(s, off); q += __shfl_down(q, off); }
    __shared__ float rs_[4], rq_[4];
    if (lane == 0) { rs_[wv] = s; rq_[wv] = q; }
    __syncthreads();
    s = rs_[0] + rs_[1] + rs_[2] + rs_[3];
    q = rq_[0] + rq_[1] + rq_[2] + rq_[3];
    const float mu = s * (1.f / DMODEL);
    const float rstd = rsqrtf(q * (1.f / DMODEL) - mu * mu + 1e-5f);
    const float4 gv = ((const float4*)g)[t];
    const float4 bv = ((const float4*)b)[t];
    float o0 = (v.x - mu) * rstd * gv.x + bv.x;
    float o1 = (v.y - mu) * rstd * gv.y + bv.y;
    float o2 = (v.z - mu) * rstd * gv.z + bv.z;
    float o3 = (v.w - mu) * rstd * gv.w + bv.w;
    if (OUTF32) {
        ((float4*)out)[(size_t)row * 256 + t] = make_float4(o0, o1, o2, o3);
    } else {
        ushort4 r4;
        r4.x = f2bf(o0); r4.y = f2bf(o1); r4.z = f2bf(o2); r4.w = f2bf(o3);
        ((ushort4*)out)[(size_t)row * 256 + t] = r4;
    }
}

// softmax over j, in-place on bf16 scores; zeroes pad cols [CTX,256)
__global__ __launch_bounds__(256) void k_softmax(u16* __restrict__ sc) {
    const size_t row = blockIdx.x;
    const int t = threadIdx.x, lane = t & 63, wv = t >> 6;
    float v = (t < CTX) ? bf2f(sc[row * 256 + t]) : -3.0e38f;
    float m = v;
#pragma unroll
    for (int off = 32; off > 0; off >>= 1) m = fmaxf(m, __shfl_down(m, off));
    __shared__ float rm[4], rsum[4];
    if (lane == 0) rm[wv] = m;
    __syncthreads();
    m = fmaxf(fmaxf(rm[0], rm[1]), fmaxf(rm[2], rm[3]));
    float e = (t < CTX) ? __expf(v - m) : 0.f;
    float s = e;
#pragma unroll
    for (int off = 32; off > 0; off >>= 1) s += __shfl_down(s, off);
    if (lane == 0) rsum[wv] = s;
    __syncthreads();
    s = rsum[0] + rsum[1] + rsum[2] + rsum[3];
    sc[row * 256 + t] = f2bf(e / s);
}

// GLU over mid[16000][4096]: a = cols [0,2048), gate = cols [2048,4096); in-place on a
__global__ __launch_bounds__(256) void k_glu(u16* __restrict__ mid) {
    const size_t r = blockIdx.x;
    const int c = threadIdx.x * 8;
    const short8 a8 = *(const short8*)(mid + r * 4096 + c);
    const short8 g8 = *(const short8*)(mid + r * 4096 + 2048 + c);
    short8 o8;
#pragma unroll
    for (int e = 0; e < 8; ++e) {
        float av = bf2f((u16)a8[e]), gg = bf2f((u16)g8[e]);
        o8[e] = (short)f2bf(av * sigmoidf_(gg));
    }
    *(short8*)(mid + r * 4096 + c) = o8;
}

// depthwise conv(K=15,pad=7)+BN(eval)+silu ; in = a-region (ld 4096), out = gate-region
__global__ __launch_bounds__(256) void k_dwconv(const u16* __restrict__ in,
                                                const float* __restrict__ w,
                                                const float* __restrict__ bng,
                                                const float* __restrict__ bnb,
                                                const float* __restrict__ bnm,
                                                const float* __restrict__ bnv,
                                                u16* __restrict__ out) {
    const int b = blockIdx.z, lt = blockIdx.x, cg = blockIdx.y;
    const int c = cg * 256 + threadIdx.x;  // 0..2047
    const int l0 = lt * 16;
    __shared__ u16 s[30][256];
#pragma unroll
    for (int rr = 0; rr < 30; ++rr) {
        int l = l0 + rr - 7;
        u16 v = 0;
        if (l >= 0 && l < 2000) v = in[((size_t)b * 2000 + l) * 4096 + c];
        s[rr][threadIdx.x] = v;
    }
    __syncthreads();
    float wv[15];
#pragma unroll
    for (int k = 0; k < 15; ++k) wv[k] = w[c * 15 + k];
    const float sc = rsqrtf(bnv[c] + 1e-5f) * bng[c];
    const float mean = bnm[c], bb = bnb[c];
#pragma unroll
    for (int l = 0; l < 16; ++l) {
        float acc = 0.f;
#pragma unroll
        for (int k = 0; k < 15; ++k) acc += bf2f(s[l + k][threadIdx.x]) * wv[k];
        float h = (acc - mean) * sc + bb;
        h = h * sigmoidf_(h);
        out[((size_t)b * 2000 + l0 + l) * 4096 + c] = f2bf(h);
    }
}

// weight transpose f32[K,N] -> bf16[N,K]
__global__ __launch_bounds__(256) void k_wt(const float* __restrict__ w, u16* __restrict__ wt,
                                            int K, int N) {
    __shared__ float tile[32][33];
    const int k0 = blockIdx.x * 32, n0 = blockIdx.y * 32;
    const int tx = threadIdx.x & 31, ty = threadIdx.x >> 5;
#pragma unroll
    for (int i = 0; i < 32; i += 8) tile[ty + i][tx] = w[(size_t)(k0 + ty + i) * N + n0 + tx];
    __syncthreads();
#pragma unroll
    for (int i = 0; i < 32; i += 8)
        wt[(size_t)(n0 + ty + i) * K + k0 + tx] = f2bf(tile[tx][ty + i]);
}

// rel_bf16[i][j][dh] = bf16(rel_emb[dist[i][j]][dh])
__global__ void k_rel(const float* __restrict__ emb, const int* __restrict__ dist,
                      u16* __restrict__ rel) {
    const int bid = blockIdx.x;
    const int d = dist[bid];
    rel[(size_t)bid * DH + threadIdx.x] = f2bf(emb[(size_t)d * DH + threadIdx.x]);
}

// vT[z][dh][j] = v_chunk[bnl*CTX+j][DMODEL + h*DH + dh], zero-padded j in [CTX,256)
__global__ __launch_bounds__(256) void k_vt(const u16* __restrict__ kvc, u16* __restrict__ vT) {
    __shared__ u16 t_[64 * 130];
    const int z = blockIdx.x, jt = blockIdx.y;
    const int bnl = z >> 3, h = z & 7;
    const int j0 = jt * 64;
    for (int idx = threadIdx.x; idx < 8192; idx += 256) {
        int j = idx >> 7, dh = idx & 127;
        int jj = j0 + j;
        u16 val = 0;
        if (jj < CTX) val = kvc[((size_t)(bnl * CTX + jj)) * (2 * DMODEL) + DMODEL + h * DH + dh];
        t_[j * 130 + dh] = val;
    }
    __syncthreads();
    for (int idx = threadIdx.x; idx < 8192; idx += 256) {
        int dh = idx >> 6, j = idx & 63;
        vT[((size_t)z * DH + dh) * 256 + j0 + j] = t_[j * 130 + dh];
    }
}

__global__ void k_fill(float* o, int n, float v) {
    int i = blockIdx.x * 256 + threadIdx.x;
    if (i < n) o[i] = v;
}

extern "C" void kernel_launch(void* const* d_in, const int* in_sizes, int n_in, void* d_out,
                              int out_size, void* d_ws, size_t ws_size, hipStream_t stream) {
    const float* x_in = (const float*)d_in[0];
    const int* dists = (const int*)d_in[1];
    const float* ff1_ln_g = (const float*)d_in[2];
    const float* ff1_ln_b = (const float*)d_in[3];
    const float* ff1_up_w = (const float*)d_in[4];
    const float* ff1_up_b = (const float*)d_in[5];
    const float* ff1_down_w = (const float*)d_in[6];
    const float* ff1_down_b = (const float*)d_in[7];
    const float* attn_ln_g = (const float*)d_in[8];
    const float* attn_ln_b = (const float*)d_in[9];
    const float* wq = (const float*)d_in[10];
    const float* wkv = (const float*)d_in[11];
    const float* wo = (const float*)d_in[12];
    const float* wo_b = (const float*)d_in[13];
    const float* rel_emb = (const float*)d_in[14];
    const float* conv_ln_g = (const float*)d_in[15];
    const float* conv_ln_b = (const float*)d_in[16];
    const float* conv_up_w = (const float*)d_in[17];
    const float* conv_up_b = (const float*)d_in[18];
    const float* dw_w = (const float*)d_in[19];
    const float* bn_g = (const float*)d_in[20];
    const float* bn_b = (const float*)d_in[21];
    const float* bn_mean = (const float*)d_in[22];
    const float* bn_var = (const float*)d_in[23];
    const float* conv_down_w = (const float*)d_in[24];
    const float* conv_down_b = (const float*)d_in[25];
    const float* ff2_ln_g = (const float*)d_in[26];
    const float* ff2_ln_b = (const float*)d_in[27];
    const float* ff2_up_w = (const float*)d_in[28];
    const float* ff2_up_b = (const float*)d_in[29];
    const float* ff2_down_w = (const float*)d_in[30];
    const float* ff2_down_b = (const float*)d_in[31];
    const float* post_ln_g = (const float*)d_in[32];
    const float* post_ln_b = (const float*)d_in[33];

    char* W = (char*)d_ws;
    size_t off = 0;
    auto alloc = [&](size_t bytes) {
        char* p = W + off;
        off += (bytes + 255) & ~(size_t)255;
        return (u16*)p;
    };
    u16* slot = alloc((size_t)4096 * 1024 * 2);
    u16* ln_buf = alloc((size_t)R_TOT * DMODEL * 2);
    u16* arena = alloc((size_t)R_TOT * DFF * 2);
    u16* mid = arena;
    u16* rel_bf = arena;
    u16* bufA = rel_bf + (size_t)CTX * CTX * DH;
    u16* bufB = bufA + (size_t)AROWS * 2 * DMODEL;
    u16* smid = bufB + (size_t)R_TOT * DMODEL;
    u16* vT = smid + (size_t)AM * CTX * 256;
    float* xs = (float*)d_out;

    if (ws_size < off) {
        k_fill<<<(out_size + 255) / 256, 256, 0, stream>>>((float*)d_out, out_size, 31337.f);
        return;
    }

    auto WT = [&](const float* s, int K, int N) {
        k_wt<<<dim3(K / 32, N / 32), 256, 0, stream>>>(s, slot, K, N);
    };

    const dim3 gUP(128, 32);  // 128^2: M=16000(->128 tiles), N=4096
    const dim3 gSQ(128, 8);   // M=16000, N=1024
    const dim3 gKV(64, 16);   // M=8000,  N=2048

    auto ff_block = [&](const float* lng, const float* lnb, const float* upw, const float* upb,
                        const float* dnw, const float* dnb, const float* resid,
                        const float* xsrc) {
        k_ln<false><<<R_TOT, 256, 0, stream>>>(xsrc, lng, lnb, ln_buf);
        WT(upw, 1024, 4096);
        k_g<1><<<gUP, 256, 0, stream>>>(ln_buf, DMODEL, slot, DMODEL, upb, 1.f, mid, DFF,
                                        nullptr, R_TOT, DFF, DMODEL);
        WT(dnw, 4096, 1024);
        k_g<2><<<gSQ, 256, 0, stream>>>(mid, DFF, slot, DFF, dnb, 0.5f, xs, DMODEL, resid,
                                        R_TOT, DMODEL, DFF);
    };

    // ---- FF1 ----
    ff_block(ff1_ln_g, ff1_ln_b, ff1_up_w, ff1_up_b, ff1_down_w, ff1_down_b, x_in, x_in);

    // ---- Attention ----
    k_ln<false><<<R_TOT, 256, 0, stream>>>(xs, attn_ln_g, attn_ln_b, ln_buf);
    k_rel<<<CTX * CTX, 128, 0, stream>>>(rel_emb, dists, rel_bf);
    WT(wq, 1024, 1024);
    k_g<0><<<gSQ, 256, 0, stream>>>(ln_buf, DMODEL, slot, DMODEL, nullptr, SCALE_Q, bufB,
                                    DMODEL, nullptr, R_TOT, DMODEL, DMODEL);
    WT(wkv, 1024, 2048);
    for (int h = 0; h < 2; ++h) {
        const int bn0 = h * ABN, m0 = bn0 * 8;
        const u16* lnc = ln_buf + (size_t)bn0 * CTX * DMODEL;
        k_g<0><<<gKV, 256, 0, stream>>>(lnc, DMODEL, slot, DMODEL, nullptr, 1.f, bufA,
                                        2 * DMODEL, nullptr, AROWS, 2 * DMODEL, DMODEL);
        k_vt<<<dim3(AM, 4), 256, 0, stream>>>(bufA, vT);
        k_qk<<<dim3(2, 2, AM), 256, 0, stream>>>(bufB, bufA, smid, bn0);
        k_pos<<<dim3(3, 2, CTX), 256, 0, stream>>>(bufB, rel_bf, smid, m0);
        k_softmax<<<AM * CTX, 256, 0, stream>>>(smid);
        k_pv<<<dim3(2, 1, AM), 256, 0, stream>>>(smid, vT, bufB, bn0);
    }
    WT(wo, 1024, 1024);
    k_g<2><<<gSQ, 256, 0, stream>>>(bufB, DMODEL, slot, DMODEL, wo_b, 1.f, xs, DMODEL, xs,
                                    R_TOT, DMODEL, DMODEL);

    // ---- Conv module: up (a|gate) -> GLU in-place -> dwconv a->gate region -> down ----
    k_ln<false><<<R_TOT, 256, 0, stream>>>(xs, conv_ln_g, conv_ln_b, ln_buf);
    WT(conv_up_w, 1024, 4096);
    k_g<0><<<gUP, 256, 0, stream>>>(ln_buf, DMODEL, slot, DMODEL, conv_up_b, 1.f, mid, DFF,
                                    nullptr, R_TOT, DFF, DMODEL);
    k_glu<<<R_TOT, 256, 0, stream>>>(mid);
    k_dwconv<<<dim3(125, 8, 8), 256, 0, stream>>>(mid, dw_w, bn_g, bn_b, bn_mean, bn_var,
                                                  mid + INNER);
    WT(conv_down_w, 2048, 1024);
    k_g<2><<<gSQ, 256, 0, stream>>>(mid + INNER, DFF, slot, INNER, conv_down_b, 1.f, xs,
                                    DMODEL, xs, R_TOT, DMODEL, INNER);

    // ---- FF2 ----
    ff_block(ff2_ln_g, ff2_ln_b, ff2_up_w, ff2_up_b, ff2_down_w, ff2_down_b, xs, xs);

    // ---- final LayerNorm (in-place on d_out) ----
    k_ln<true><<<R_TOT, 256, 0, stream>>>(xs, post_ln_g, post_ln_b, d_out);
}

// Round 18
// 1628.344 us; speedup vs baseline: 1.1871x; 1.0315x over previous
//
#include <hip/hip_runtime.h>

typedef unsigned short u16;
typedef unsigned int u32;
using short8 = __attribute__((ext_vector_type(8))) short;
using floatx4 = __attribute__((ext_vector_type(4))) float;

#define DMODEL 1024
#define DFF 4096
#define INNER 2048
#define DH 128
#define CTX 200
#define R_TOT 16000
#define ABN 40
#define AROWS (ABN * CTX)
#define AM (ABN * 8)
#define SCALE_Q 0.08838834764831845f

__device__ __forceinline__ u16 f2bf(float f) {
    union { float f; u32 u; } v; v.f = f;
    u32 r = v.u + 0x7FFFu + ((v.u >> 16) & 1u);
    return (u16)(r >> 16);
}
__device__ __forceinline__ float bf2f(u16 u) {
    union { u32 u; float f; } v; v.u = ((u32)u) << 16; return v.f;
}
__device__ __forceinline__ float sigmoidf_(float x) { return 1.f / (1.f + __expf(-x)); }

__device__ __forceinline__ void load_lds16(const void* g, void* l) {
    __builtin_amdgcn_global_load_lds((const __attribute__((address_space(1))) u32*)g,
                                     (__attribute__((address_space(3))) u32*)l, 16, 0, 0);
}

// XCD stripe-cluster remap: gx MUST be a multiple of 8 (pad blocks early-exit on row0>=M).
__device__ __forceinline__ void xcd_stripe_remap(int& bx, int& by) {
    const int gx = gridDim.x;
    const int gxs = gx >> 3;
    const int id = blockIdx.y * gx + blockIdx.x;
    const int xcd = id & 7;
    const int local = id >> 3;
    bx = xcd * gxs + (local % gxs);
    by = local / gxs;
}

// epilogue: MODE 0 bf16=alpha*v+bias ; 1 bf16=silu(v+bias) ; 2 f32=alpha*(v+bias)+resid
template <int MODE>
__device__ __forceinline__ void epi_store(int r, int c, float v, int M, int ldc,
                                          const float* bias, float alpha, void* out,
                                          const float* resid) {
    if (r >= M) return;
    size_t idx = (size_t)r * ldc + c;
    float bb = bias ? bias[c] : 0.f;
    if (MODE == 0) {
        ((u16*)out)[idx] = f2bf(alpha * v + bb);
    } else if (MODE == 1) {
        float t = v + bb;
        ((u16*)out)[idx] = f2bf(t * sigmoidf_(t));
    } else {
        ((float*)out)[idx] = alpha * (v + bb) + resid[idx];
    }
}

// ====== k_g: 128x128, 4 waves, 32KB single-buffer, 2-barrier, 4 blocks/CU ======
// Co-residency (m114 implicit cross-block overlap) is the verified lever: another
// block's MFMA hides this block's vmcnt(0)+barrier drain. 60 VGPR + 64 AGPR = 124
// <= 2048/16 -> no spill at 16 waves/CU; LDS 4x32KB = 128 <= 160KB.
template <int MODE>
__global__ __launch_bounds__(256, 4) void k_g(const u16* __restrict__ A, int lda,
                                              const u16* __restrict__ Bt, int ldb,
                                              const float* __restrict__ bias, float alpha,
                                              void* out, int ldc, const float* resid, int M,
                                              int N, int K) {
    __shared__ __align__(128) char lds[32768];
    int bx, by;
    xcd_stripe_remap(bx, by);
    const int row0 = bx * 128, col0 = by * 128;
    if (row0 >= M) return;
    const int lane = threadIdx.x & 63;
    const int wave = threadIdx.x >> 6;
    const int wrow = (wave >> 1) * 64;
    const int wcol = (wave & 1) * 64;
    const int lr = lane & 15;
    const int kg = lane >> 4;
    const int nt = K >> 6;

    const char* sA[4];
    const char* sB[4];
#pragma unroll
    for (int r = 0; r < 4; ++r) {
        int o = r * 4096 + wave * 1024 + lane * 16;
        int row = o >> 7;
        int srcb = (o & 127) ^ ((row & 7) << 4);
        int ga = row0 + row;
        ga = (ga < M) ? ga : M - 1;
        sA[r] = (const char*)A + (size_t)ga * ((size_t)lda * 2) + srcb;
        int gb = col0 + row;
        gb = (gb < N) ? gb : N - 1;
        sB[r] = (const char*)Bt + (size_t)gb * ((size_t)ldb * 2) + srcb;
    }
    floatx4 acc[4][4];
#pragma unroll
    for (int i = 0; i < 4; ++i)
#pragma unroll
        for (int j = 0; j < 4; ++j) acc[i][j] = (floatx4){0.f, 0.f, 0.f, 0.f};

    for (int t = 0; t < nt; ++t) {
        const int kb = t << 7;
#pragma unroll
        for (int r = 0; r < 4; ++r) {
            load_lds16(sA[r] + kb, lds + r * 4096 + wave * 1024);
            load_lds16(sB[r] + kb, lds + 16384 + r * 4096 + wave * 1024);
        }
        asm volatile("s_waitcnt vmcnt(0)" ::: "memory");
        __builtin_amdgcn_s_barrier();
#pragma unroll
        for (int ks = 0; ks < 2; ++ks) {
            short8 av[4], bv[4];
#pragma unroll
            for (int mi = 0; mi < 4; ++mi) {
                int row = wrow + mi * 16 + lr;
                int cb = (ks * 64 + kg * 16) ^ ((row & 7) << 4);
                av[mi] = *(const short8*)(lds + row * 128 + cb);
            }
#pragma unroll
            for (int ni = 0; ni < 4; ++ni) {
                int row = wcol + ni * 16 + lr;
                int cb = (ks * 64 + kg * 16) ^ ((row & 7) << 4);
                bv[ni] = *(const short8*)(lds + 16384 + row * 128 + cb);
            }
#pragma unroll
            for (int mi = 0; mi < 4; ++mi)
#pragma unroll
                for (int ni = 0; ni < 4; ++ni)
                    acc[mi][ni] = __builtin_amdgcn_mfma_f32_16x16x32_bf16(av[mi], bv[ni],
                                                                          acc[mi][ni], 0, 0, 0);
        }
        asm volatile("s_waitcnt lgkmcnt(0)" ::: "memory");
        __builtin_amdgcn_s_barrier();
    }
#pragma unroll
    for (int mi = 0; mi < 4; ++mi)
#pragma unroll
        for (int ni = 0; ni < 4; ++ni)
#pragma unroll
            for (int rr = 0; rr < 4; ++rr)
                epi_store<MODE>(row0 + wrow + mi * 16 + kg * 4 + rr, col0 + wcol + ni * 16 + lr,
                                acc[mi][ni][rr], M, ldc, bias, alpha, out, resid);
}

// ====== attention-internal core: single-buffer 32KB, 2-barrier, 4 blocks/CU ======
template <typename RowMap>
__device__ __forceinline__ void stage_tile_s(const char* __restrict__ src, RowMap rowoff,
                                             int nrows, int row0, int k0b, char* tile) {
    const int lane = threadIdx.x & 63;
    const int wave = threadIdx.x >> 6;
#pragma unroll
    for (int r = 0; r < 4; ++r) {
        int o = r * 4096 + wave * 1024 + lane * 16;
        int row = o >> 7;
        int srcb = (o & 127) ^ ((row & 7) << 4);
        int grow = row0 + row;
        grow = (grow < nrows) ? grow : (nrows - 1);
        load_lds16(src + rowoff(grow) + k0b + srcb, tile + r * 4096 + wave * 1024);
    }
}

template <typename RMA, typename RMB, typename Epi>
__device__ __forceinline__ void gemm_core_s(const char* __restrict__ A, RMA rma, int a_rows,
                                            const char* __restrict__ B, RMB rmb, int b_rows,
                                            int K, int row0, int col0, char* lds, Epi epi) {
    const int lane = threadIdx.x & 63;
    const int wave = threadIdx.x >> 6;
    const int wrow = (wave >> 1) * 64;
    const int wcol = (wave & 1) * 64;
    const int lr = lane & 15;
    const int kg = lane >> 4;
    const int nt = K >> 6;

    floatx4 acc[4][4];
#pragma unroll
    for (int i = 0; i < 4; ++i)
#pragma unroll
        for (int j = 0; j < 4; ++j) acc[i][j] = (floatx4){0.f, 0.f, 0.f, 0.f};

    for (int t = 0; t < nt; ++t) {
        const int kb = t << 7;
        stage_tile_s(A, rma, a_rows, row0, kb, lds);
        stage_tile_s(B, rmb, b_rows, col0, kb, lds + 16384);
        asm volatile("s_waitcnt vmcnt(0)" ::: "memory");
        __builtin_amdgcn_s_barrier();
#pragma unroll
        for (int ks = 0; ks < 2; ++ks) {
            short8 av[4], bv[4];
#pragma unroll
            for (int mi = 0; mi < 4; ++mi) {
                int row = wrow + mi * 16 + lr;
                int cb = (ks * 64 + kg * 16) ^ ((row & 7) << 4);
                av[mi] = *(const short8*)(lds + row * 128 + cb);
            }
#pragma unroll
            for (int ni = 0; ni < 4; ++ni) {
                int row = wcol + ni * 16 + lr;
                int cb = (ks * 64 + kg * 16) ^ ((row & 7) << 4);
                bv[ni] = *(const short8*)(lds + 16384 + row * 128 + cb);
            }
#pragma unroll
            for (int mi = 0; mi < 4; ++mi)
#pragma unroll
                for (int ni = 0; ni < 4; ++ni)
                    acc[mi][ni] = __builtin_amdgcn_mfma_f32_16x16x32_bf16(av[mi], bv[ni],
                                                                          acc[mi][ni], 0, 0, 0);
        }
        asm volatile("s_waitcnt lgkmcnt(0)" ::: "memory");
        __builtin_amdgcn_s_barrier();
    }
#pragma unroll
    for (int mi = 0; mi < 4; ++mi)
#pragma unroll
        for (int ni = 0; ni < 4; ++ni)
#pragma unroll
            for (int rr = 0; rr < 4; ++rr)
                epi(row0 + wrow + mi * 16 + kg * 4 + rr, col0 + wcol + ni * 16 + lr,
                    acc[mi][ni][rr]);
}

// scores[z][i][j] = q_scaled[i].k[j]  (bf16, cols padded to 256), z = local bnh
__global__ __launch_bounds__(256, 4) void k_qk(const u16* __restrict__ q,
                                               const u16* __restrict__ kvc,
                                               u16* __restrict__ sc, int bn0) {
    __shared__ __align__(128) char lds[32768];
    const int z = blockIdx.z, bnl = z >> 3, h = z & 7;
    const char* A = (const char*)(q + ((size_t)(bn0 + bnl) * CTX) * DMODEL + h * DH);
    const char* B = (const char*)(kvc + ((size_t)bnl * CTX) * (2 * DMODEL) + h * DH);
    u16* out = sc + (size_t)z * CTX * 256;
    gemm_core_s(A, [](int r) { return (size_t)r * (DMODEL * 2); }, CTX, B,
                [](int r) { return (size_t)r * (4 * DMODEL); }, CTX, DH, blockIdx.x * 128,
                blockIdx.y * 128, lds, [&](int r, int c, float v) {
                    if (r < CTX) out[(size_t)r * 256 + c] = f2bf(v);
                });
}

// scores[m][i][j] += q'[m].rel[i][j]  (batched over i; A gathered from q via row map)
__global__ __launch_bounds__(256, 4) void k_pos(const u16* __restrict__ q,
                                                const u16* __restrict__ rel,
                                                u16* __restrict__ sc, int m0) {
    __shared__ __align__(128) char lds[32768];
    const int i = blockIdx.z;
    const char* B = (const char*)(rel + (size_t)i * CTX * DH);
    u16* out = sc + i * 256;
    gemm_core_s((const char*)q,
                [=](int r) {
                    int m = m0 + r;
                    return (size_t)(((m >> 3) * CTX + i) * DMODEL + (m & 7) * DH) * 2;
                },
                AM, B, [](int r) { return (size_t)r * (DH * 2); }, CTX, DH, blockIdx.x * 128,
                blockIdx.y * 128, lds, [&](int r, int c, float v) {
                    if (r < AM) {
                        size_t idx = (size_t)r * (CTX * 256) + c;
                        out[idx] = f2bf(bf2f(out[idx]) + v);
                    }
                });
}

// attn_out[(bn0+z/8)*CTX+i][(z&7)*DH+dh] = P[z][i][:].vT[z][dh][:]  (K=256 padded)
__global__ __launch_bounds__(256, 4) void k_pv(const u16* __restrict__ P,
                                               const u16* __restrict__ vT,
                                               u16* __restrict__ attn, int bn0) {
    __shared__ __align__(128) char lds[32768];
    const int z = blockIdx.z;
    u16* out = attn + ((size_t)(bn0 + (z >> 3)) * CTX) * DMODEL + (z & 7) * DH;
    const char* A = (const char*)(P + (size_t)z * CTX * 256);
    const char* B = (const char*)(vT + (size_t)z * DH * 256);
    gemm_core_s(A, [](int r) { return (size_t)r * 512; }, CTX, B,
                [](int r) { return (size_t)r * 512; }, DH, 256, blockIdx.x * 128, 0, lds,
                [&](int r, int c, float v) {
                    if (r < CTX) out[(size_t)r * DMODEL + c] = f2bf(v);
                });
}

// ---------------- LayerNorm: wave-per-row, 4 rows/block, in-wave reduction ----------------
template <bool OUTF32>
__global__ __launch_bounds__(256) void k_ln(const float* __restrict__ x,
                                            const float* __restrict__ g,
                                            const float* __restrict__ b, void* __restrict__ out) {
    const int wv = threadIdx.x >> 6, lane = threadIdx.x & 63;
    const int row = blockIdx.x * 4 + wv;  // grid = R_TOT/4
    const float4* xr = (const float4*)(x + (size_t)row * DMODEL);
    float4 v[4];
    float s = 0.f, q = 0.f;
#pragma unroll
    for (int i = 0; i < 4; ++i) {
        v[i] = xr[lane + i * 64];
        s += v[i].x + v[i].y + v[i].z + v[i].w;
        q += v[i].x * v[i].x + v[i].y * v[i].y + v[i].z * v[i].z + v[i].w * v[i].w;
    }
#pragma unroll
    for (int off = 32; off > 0; off >>= 1) { s += __shfl_down(s, off); q += __shfl_down(q, off); }
    s = __shfl(s, 0);
    q = __shfl(q, 0);
    const float mu = s * (1.f / DMODEL);
    const float rstd = rsqrtf(q * (1.f / DMODEL) - mu * mu + 1e-5f);
#pragma unroll
    for (int i = 0; i < 4; ++i) {
        const float4 gv = ((const float4*)g)[lane + i * 64];
        const float4 bv = ((const float4*)b)[lane + i * 64];
        float o0 = (v[i].x - mu) * rstd * gv.x + bv.x;
        float o1 = (v[i].y - mu) * rstd * gv.y + bv.y;
        float o2 = (v[i].z - mu) * rstd * gv.z + bv.z;
        float o3 = (v[i].w - mu) * rstd * gv.w + bv.w;
        if (OUTF32) {
            ((float4*)out)[(size_t)row * 256 + lane + i * 64] = make_float4(o0, o1, o2, o3);
        } else {
            ushort4 r4;
            r4.x = f2bf(o0); r4.y = f2bf(o1); r4.z = f2bf(o2); r4.w = f2bf(o3);
            ((ushort4*)out)[(size_t)row * 256 + lane + i * 64] = r4;
        }
    }
}

// softmax over j: wave-per-row, 4 rows/block; in-place bf16; zeroes pad cols [CTX,256)
__global__ __launch_bounds__(256) void k_softmax(u16* __restrict__ sc) {
    const int wv = threadIdx.x >> 6, lane = threadIdx.x & 63;
    const size_t row = (size_t)blockIdx.x * 4 + wv;  // grid = rows/4
    u16* p = sc + row * 256;
    const ushort4 d = ((const ushort4*)p)[lane];  // cols lane*4 .. lane*4+3
    float f[4];
    const u16 dv[4] = {d.x, d.y, d.z, d.w};
#pragma unroll
    for (int e = 0; e < 4; ++e)
        f[e] = (lane * 4 + e < CTX) ? bf2f(dv[e]) : -3.0e38f;
    float m = fmaxf(fmaxf(f[0], f[1]), fmaxf(f[2], f[3]));
#pragma unroll
    for (int off = 32; off > 0; off >>= 1) m = fmaxf(m, __shfl_down(m, off));
    m = __shfl(m, 0);
    float e4[4];
    float s = 0.f;
#pragma unroll
    for (int e = 0; e < 4; ++e) {
        e4[e] = (lane * 4 + e < CTX) ? __expf(f[e] - m) : 0.f;
        s += e4[e];
    }
#pragma unroll
    for (int off = 32; off > 0; off >>= 1) s += __shfl_down(s, off);
    s = __shfl(s, 0);
    const float inv = 1.f / s;
    ushort4 o;
    o.x = f2bf(e4[0] * inv);
    o.y = f2bf(e4[1] * inv);
    o.z = f2bf(e4[2] * inv);
    o.w = f2bf(e4[3] * inv);
    ((ushort4*)p)[lane] = o;
}

// GLU over mid[16000][4096]: a = cols [0,2048), gate = cols [2048,4096); in-place on a
__global__ __launch_bounds__(256) void k_glu(u16* __restrict__ mid) {
    const size_t r = blockIdx.x;
    const int c = threadIdx.x * 8;
    const short8 a8 = *(const short8*)(mid + r * 4096 + c);
    const short8 g8 = *(const short8*)(mid + r * 4096 + 2048 + c);
    short8 o8;
#pragma unroll
    for (int e = 0; e < 8; ++e) {
        float av = bf2f((u16)a8[e]), gg = bf2f((u16)g8[e]);
        o8[e] = (short)f2bf(av * sigmoidf_(gg));
    }
    *(short8*)(mid + r * 4096 + c) = o8;
}

// depthwise conv(K=15,pad=7)+BN(eval)+silu ; in = a-region (ld 4096), out = gate-region
__global__ __launch_bounds__(256) void k_dwconv(const u16* __restrict__ in,
                                                const float* __restrict__ w,
                                                const float* __restrict__ bng,
                                                const float* __restrict__ bnb,
                                                const float* __restrict__ bnm,
                                                const float* __restrict__ bnv,
                                                u16* __restrict__ out) {
    const int b = blockIdx.z, lt = blockIdx.x, cg = blockIdx.y;
    const int c = cg * 256 + threadIdx.x;  // 0..2047
    const int l0 = lt * 16;
    __shared__ u16 s[30][256];
#pragma unroll
    for (int rr = 0; rr < 30; ++rr) {
        int l = l0 + rr - 7;
        u16 v = 0;
        if (l >= 0 && l < 2000) v = in[((size_t)b * 2000 + l) * 4096 + c];
        s[rr][threadIdx.x] = v;
    }
    __syncthreads();
    float wv[15];
#pragma unroll
    for (int k = 0; k < 15; ++k) wv[k] = w[c * 15 + k];
    const float sc = rsqrtf(bnv[c] + 1e-5f) * bng[c];
    const float mean = bnm[c], bb = bnb[c];
#pragma unroll
    for (int l = 0; l < 16; ++l) {
        float acc = 0.f;
#pragma unroll
        for (int k = 0; k < 15; ++k) acc += bf2f(s[l + k][threadIdx.x]) * wv[k];
        float h = (acc - mean) * sc + bb;
        h = h * sigmoidf_(h);
        out[((size_t)b * 2000 + l0 + l) * 4096 + c] = f2bf(h);
    }
}

// weight transpose f32[K,N] -> bf16[N,K]
__global__ __launch_bounds__(256) void k_wt(const float* __restrict__ w, u16* __restrict__ wt,
                                            int K, int N) {
    __shared__ float tile[32][33];
    const int k0 = blockIdx.x * 32, n0 = blockIdx.y * 32;
    const int tx = threadIdx.x & 31, ty = threadIdx.x >> 5;
#pragma unroll
    for (int i = 0; i < 32; i += 8) tile[ty + i][tx] = w[(size_t)(k0 + ty + i) * N + n0 + tx];
    __syncthreads();
#pragma unroll
    for (int i = 0; i < 32; i += 8)
        wt[(size_t)(n0 + ty + i) * K + k0 + tx] = f2bf(tile[tx][ty + i]);
}

// rel_bf16[i][j][dh] = bf16(rel_emb[dist[i][j]][dh])
__global__ void k_rel(const float* __restrict__ emb, const int* __restrict__ dist,
                      u16* __restrict__ rel) {
    const int bid = blockIdx.x;
    const int d = dist[bid];
    rel[(size_t)bid * DH + threadIdx.x] = f2bf(emb[(size_t)d * DH + threadIdx.x]);
}

// vT[z][dh][j] = v_chunk[bnl*CTX+j][DMODEL + h*DH + dh], zero-padded j in [CTX,256)
__global__ __launch_bounds__(256) void k_vt(const u16* __restrict__ kvc, u16* __restrict__ vT) {
    __shared__ u16 t_[64 * 130];
    const int z = blockIdx.x, jt = blockIdx.y;
    const int bnl = z >> 3, h = z & 7;
    const int j0 = jt * 64;
    for (int idx = threadIdx.x; idx < 8192; idx += 256) {
        int j = idx >> 7, dh = idx & 127;
        int jj = j0 + j;
        u16 val = 0;
        if (jj < CTX) val = kvc[((size_t)(bnl * CTX + jj)) * (2 * DMODEL) + DMODEL + h * DH + dh];
        t_[j * 130 + dh] = val;
    }
    __syncthreads();
    for (int idx = threadIdx.x; idx < 8192; idx += 256) {
        int dh = idx >> 6, j = idx & 63;
        vT[((size_t)z * DH + dh) * 256 + j0 + j] = t_[j * 130 + dh];
    }
}

__global__ void k_fill(float* o, int n, float v) {
    int i = blockIdx.x * 256 + threadIdx.x;
    if (i < n) o[i] = v;
}

extern "C" void kernel_launch(void* const* d_in, const int* in_sizes, int n_in, void* d_out,
                              int out_size, void* d_ws, size_t ws_size, hipStream_t stream) {
    const float* x_in = (const float*)d_in[0];
    const int* dists = (const int*)d_in[1];
    const float* ff1_ln_g = (const float*)d_in[2];
    const float* ff1_ln_b = (const float*)d_in[3];
    const float* ff1_up_w = (const float*)d_in[4];
    const float* ff1_up_b = (const float*)d_in[5];
    const float* ff1_down_w = (const float*)d_in[6];
    const float* ff1_down_b = (const float*)d_in[7];
    const float* attn_ln_g = (const float*)d_in[8];
    const float* attn_ln_b = (const float*)d_in[9];
    const float* wq = (const float*)d_in[10];
    const float* wkv = (const float*)d_in[11];
    const float* wo = (const float*)d_in[12];
    const float* wo_b = (const float*)d_in[13];
    const float* rel_emb = (const float*)d_in[14];
    const float* conv_ln_g = (const float*)d_in[15];
    const float* conv_ln_b = (const float*)d_in[16];
    const float* conv_up_w = (const float*)d_in[17];
    const float* conv_up_b = (const float*)d_in[18];
    const float* dw_w = (const float*)d_in[19];
    const float* bn_g = (const float*)d_in[20];
    const float* bn_b = (const float*)d_in[21];
    const float* bn_mean = (const float*)d_in[22];
    const float* bn_var = (const float*)d_in[23];
    const float* conv_down_w = (const float*)d_in[24];
    const float* conv_down_b = (const float*)d_in[25];
    const float* ff2_ln_g = (const float*)d_in[26];
    const float* ff2_ln_b = (const float*)d_in[27];
    const float* ff2_up_w = (const float*)d_in[28];
    const float* ff2_up_b = (const float*)d_in[29];
    const float* ff2_down_w = (const float*)d_in[30];
    const float* ff2_down_b = (const float*)d_in[31];
    const float* post_ln_g = (const float*)d_in[32];
    const float* post_ln_b = (const float*)d_in[33];

    char* W = (char*)d_ws;
    size_t off = 0;
    auto alloc = [&](size_t bytes) {
        char* p = W + off;
        off += (bytes + 255) & ~(size_t)255;
        return (u16*)p;
    };
    u16* slot = alloc((size_t)4096 * 1024 * 2);
    u16* ln_buf = alloc((size_t)R_TOT * DMODEL * 2);
    u16* arena = alloc((size_t)R_TOT * DFF * 2);
    u16* mid = arena;
    u16* rel_bf = arena;
    u16* bufA = rel_bf + (size_t)CTX * CTX * DH;
    u16* bufB = bufA + (size_t)AROWS * 2 * DMODEL;
    u16* smid = bufB + (size_t)R_TOT * DMODEL;
    u16* vT = smid + (size_t)AM * CTX * 256;
    float* xs = (float*)d_out;

    if (ws_size < off) {
        k_fill<<<(out_size + 255) / 256, 256, 0, stream>>>((float*)d_out, out_size, 31337.f);
        return;
    }

    auto WT = [&](const float* s, int K, int N) {
        k_wt<<<dim3(K / 32, N / 32), 256, 0, stream>>>(s, slot, K, N);
    };

    const dim3 gUP(128, 32);  // 128^2: M=16000(->128 tiles), N=4096
    const dim3 gSQ(128, 8);   // M=16000, N=1024
    const dim3 gKV(64, 16);   // M=8000,  N=2048

    auto ff_block = [&](const float* lng, const float* lnb, const float* upw, const float* upb,
                        const float* dnw, const float* dnb, const float* resid,
                        const float* xsrc) {
        k_ln<false><<<R_TOT / 4, 256, 0, stream>>>(xsrc, lng, lnb, ln_buf);
        WT(upw, 1024, 4096);
        k_g<1><<<gUP, 256, 0, stream>>>(ln_buf, DMODEL, slot, DMODEL, upb, 1.f, mid, DFF,
                                        nullptr, R_TOT, DFF, DMODEL);
        WT(dnw, 4096, 1024);
        k_g<2><<<gSQ, 256, 0, stream>>>(mid, DFF, slot, DFF, dnb, 0.5f, xs, DMODEL, resid,
                                        R_TOT, DMODEL, DFF);
    };

    // ---- FF1 ----
    ff_block(ff1_ln_g, ff1_ln_b, ff1_up_w, ff1_up_b, ff1_down_w, ff1_down_b, x_in, x_in);

    // ---- Attention ----
    k_ln<false><<<R_TOT / 4, 256, 0, stream>>>(xs, attn_ln_g, attn_ln_b, ln_buf);
    k_rel<<<CTX * CTX, 128, 0, stream>>>(rel_emb, dists, rel_bf);
    WT(wq, 1024, 1024);
    k_g<0><<<gSQ, 256, 0, stream>>>(ln_buf, DMODEL, slot, DMODEL, nullptr, SCALE_Q, bufB,
                                    DMODEL, nullptr, R_TOT, DMODEL, DMODEL);
    WT(wkv, 1024, 2048);
    for (int h = 0; h < 2; ++h) {
        const int bn0 = h * ABN, m0 = bn0 * 8;
        const u16* lnc = ln_buf + (size_t)bn0 * CTX * DMODEL;
        k_g<0><<<gKV, 256, 0, stream>>>(lnc, DMODEL, slot, DMODEL, nullptr, 1.f, bufA,
                                        2 * DMODEL, nullptr, AROWS, 2 * DMODEL, DMODEL);
        k_vt<<<dim3(AM, 4), 256, 0, stream>>>(bufA, vT);
        k_qk<<<dim3(2, 2, AM), 256, 0, stream>>>(bufB, bufA, smid, bn0);
        k_pos<<<dim3(3, 2, CTX), 256, 0, stream>>>(bufB, rel_bf, smid, m0);
        k_softmax<<<AM * CTX / 4, 256, 0, stream>>>(smid);
        k_pv<<<dim3(2, 1, AM), 256, 0, stream>>>(smid, vT, bufB, bn0);
    }
    WT(wo, 1024, 1024);
    k_g<2><<<gSQ, 256, 0, stream>>>(bufB, DMODEL, slot, DMODEL, wo_b, 1.f, xs, DMODEL, xs,
                                    R_TOT, DMODEL, DMODEL);

    // ---- Conv module: up (a|gate) -> GLU in-place -> dwconv a->gate region -> down ----
    k_ln<false><<<R_TOT / 4, 256, 0, stream>>>(xs, conv_ln_g, conv_ln_b, ln_buf);
    WT(conv_up_w, 1024, 4096);
    k_g<0><<<gUP, 256, 0, stream>>>(ln_buf, DMODEL, slot, DMODEL, conv_up_b, 1.f, mid, DFF,
                                    nullptr, R_TOT, DFF, DMODEL);
    k_glu<<<R_TOT, 256, 0, stream>>>(mid);
    k_dwconv<<<dim3(125, 8, 8), 256, 0, stream>>>(mid, dw_w, bn_g, bn_b, bn_mean, bn_var,
                                                  mid + INNER);
    WT(conv_down_w, 2048, 1024);
    k_g<2><<<gSQ, 256, 0, stream>>>(mid + INNER, DFF, slot, INNER, conv_down_b, 1.f, xs,
                                    DMODEL, xs, R_TOT, DMODEL, INNER);

    // ---- FF2 ----
    ff_block(ff2_ln_g, ff2_ln_b, ff2_up_w, ff2_up_b, ff2_down_w, ff2_down_b, xs, xs);

    // ---- final LayerNorm (in-place on d_out) ----
    k_ln<true><<<R_TOT / 4, 256, 0, stream>>>(xs, post_ln_g, post_ln_b, d_out);
}

// Round 19
// 1606.469 us; speedup vs baseline: 1.2033x; 1.0136x over previous
//
#include <hip/hip_runtime.h>

typedef unsigned short u16;
typedef unsigned int u32;
using short8 = __attribute__((ext_vector_type(8))) short;
using floatx4 = __attribute__((ext_vector_type(4))) float;

#define DMODEL 1024
#define DFF 4096
#define INNER 2048
#define DH 128
#define CTX 200
#define R_TOT 16000
#define ABN 40
#define AROWS (ABN * CTX)
#define AM (ABN * 8)
#define SCALE_Q 0.08838834764831845f

__device__ __forceinline__ u16 f2bf(float f) {
    union { float f; u32 u; } v; v.f = f;
    u32 r = v.u + 0x7FFFu + ((v.u >> 16) & 1u);
    return (u16)(r >> 16);
}
__device__ __forceinline__ float bf2f(u16 u) {
    union { u32 u; float f; } v; v.u = ((u32)u) << 16; return v.f;
}
__device__ __forceinline__ float sigmoidf_(float x) { return 1.f / (1.f + __expf(-x)); }

__device__ __forceinline__ void load_lds16(const void* g, void* l) {
    __builtin_amdgcn_global_load_lds((const __attribute__((address_space(1))) u32*)g,
                                     (__attribute__((address_space(3))) u32*)l, 16, 0, 0);
}

// XCD stripe-cluster remap: gx MUST be a multiple of 8 (pad blocks early-exit on row0>=M).
__device__ __forceinline__ void xcd_stripe_remap(int& bx, int& by) {
    const int gx = gridDim.x;
    const int gxs = gx >> 3;
    const int id = blockIdx.y * gx + blockIdx.x;
    const int xcd = id & 7;
    const int local = id >> 3;
    bx = xcd * gxs + (local % gxs);
    by = local / gxs;
}

// epilogue: MODE 0 bf16=alpha*v+bias ; 1 bf16=silu(v+bias) ; 2 f32=alpha*(v+bias)+resid
template <int MODE>
__device__ __forceinline__ void epi_store(int r, int c, float v, int M, int ldc,
                                          const float* bias, float alpha, void* out,
                                          const float* resid) {
    if (r >= M) return;
    size_t idx = (size_t)r * ldc + c;
    float bb = bias ? bias[c] : 0.f;
    if (MODE == 0) {
        ((u16*)out)[idx] = f2bf(alpha * v + bb);
    } else if (MODE == 1) {
        float t = v + bb;
        ((u16*)out)[idx] = f2bf(t * sigmoidf_(t));
    } else {
        ((float*)out)[idx] = alpha * (v + bb) + resid[idx];
    }
}

// ====== k_g: 128x128, 4 waves, 32KB single-buffer, 2-barrier, 4 blocks/CU ======
// Co-residency (m114 implicit cross-block overlap) is the verified lever: another
// block's MFMA hides this block's vmcnt(0)+barrier drain. 60 VGPR + 64 AGPR = 124
// <= 2048/16 -> no spill at 16 waves/CU; LDS 4x32KB = 128 <= 160KB.
template <int MODE>
__global__ __launch_bounds__(256, 4) void k_g(const u16* __restrict__ A, int lda,
                                              const u16* __restrict__ Bt, int ldb,
                                              const float* __restrict__ bias, float alpha,
                                              void* out, int ldc, const float* resid, int M,
                                              int N, int K) {
    __shared__ __align__(128) char lds[32768];
    int bx, by;
    xcd_stripe_remap(bx, by);
    const int row0 = bx * 128, col0 = by * 128;
    if (row0 >= M) return;
    const int lane = threadIdx.x & 63;
    const int wave = threadIdx.x >> 6;
    const int wrow = (wave >> 1) * 64;
    const int wcol = (wave & 1) * 64;
    const int lr = lane & 15;
    const int kg = lane >> 4;
    const int nt = K >> 6;

    const char* sA[4];
    const char* sB[4];
#pragma unroll
    for (int r = 0; r < 4; ++r) {
        int o = r * 4096 + wave * 1024 + lane * 16;
        int row = o >> 7;
        int srcb = (o & 127) ^ ((row & 7) << 4);
        int ga = row0 + row;
        ga = (ga < M) ? ga : M - 1;
        sA[r] = (const char*)A + (size_t)ga * ((size_t)lda * 2) + srcb;
        int gb = col0 + row;
        gb = (gb < N) ? gb : N - 1;
        sB[r] = (const char*)Bt + (size_t)gb * ((size_t)ldb * 2) + srcb;
    }
    floatx4 acc[4][4];
#pragma unroll
    for (int i = 0; i < 4; ++i)
#pragma unroll
        for (int j = 0; j < 4; ++j) acc[i][j] = (floatx4){0.f, 0.f, 0.f, 0.f};

    for (int t = 0; t < nt; ++t) {
        const int kb = t << 7;
#pragma unroll
        for (int r = 0; r < 4; ++r) {
            load_lds16(sA[r] + kb, lds + r * 4096 + wave * 1024);
            load_lds16(sB[r] + kb, lds + 16384 + r * 4096 + wave * 1024);
        }
        asm volatile("s_waitcnt vmcnt(0)" ::: "memory");
        __builtin_amdgcn_s_barrier();
#pragma unroll
        for (int ks = 0; ks < 2; ++ks) {
            short8 av[4], bv[4];
#pragma unroll
            for (int mi = 0; mi < 4; ++mi) {
                int row = wrow + mi * 16 + lr;
                int cb = (ks * 64 + kg * 16) ^ ((row & 7) << 4);
                av[mi] = *(const short8*)(lds + row * 128 + cb);
            }
#pragma unroll
            for (int ni = 0; ni < 4; ++ni) {
                int row = wcol + ni * 16 + lr;
                int cb = (ks * 64 + kg * 16) ^ ((row & 7) << 4);
                bv[ni] = *(const short8*)(lds + 16384 + row * 128 + cb);
            }
#pragma unroll
            for (int mi = 0; mi < 4; ++mi)
#pragma unroll
                for (int ni = 0; ni < 4; ++ni)
                    acc[mi][ni] = __builtin_amdgcn_mfma_f32_16x16x32_bf16(av[mi], bv[ni],
                                                                          acc[mi][ni], 0, 0, 0);
        }
        asm volatile("s_waitcnt lgkmcnt(0)" ::: "memory");
        __builtin_amdgcn_s_barrier();
    }
#pragma unroll
    for (int mi = 0; mi < 4; ++mi)
#pragma unroll
        for (int ni = 0; ni < 4; ++ni)
#pragma unroll
            for (int rr = 0; rr < 4; ++rr)
                epi_store<MODE>(row0 + wrow + mi * 16 + kg * 4 + rr, col0 + wcol + ni * 16 + lr,
                                acc[mi][ni][rr], M, ldc, bias, alpha, out, resid);
}

// ====== attention-internal core: single-buffer 32KB, 2-barrier, 4 blocks/CU ======
template <typename RowMap>
__device__ __forceinline__ void stage_tile_s(const char* __restrict__ src, RowMap rowoff,
                                             int nrows, int row0, int k0b, char* tile) {
    const int lane = threadIdx.x & 63;
    const int wave = threadIdx.x >> 6;
#pragma unroll
    for (int r = 0; r < 4; ++r) {
        int o = r * 4096 + wave * 1024 + lane * 16;
        int row = o >> 7;
        int srcb = (o & 127) ^ ((row & 7) << 4);
        int grow = row0 + row;
        grow = (grow < nrows) ? grow : (nrows - 1);
        load_lds16(src + rowoff(grow) + k0b + srcb, tile + r * 4096 + wave * 1024);
    }
}

template <typename RMA, typename RMB, typename Epi>
__device__ __forceinline__ void gemm_core_s(const char* __restrict__ A, RMA rma, int a_rows,
                                            const char* __restrict__ B, RMB rmb, int b_rows,
                                            int K, int row0, int col0, char* lds, Epi epi) {
    const int lane = threadIdx.x & 63;
    const int wave = threadIdx.x >> 6;
    const int wrow = (wave >> 1) * 64;
    const int wcol = (wave & 1) * 64;
    const int lr = lane & 15;
    const int kg = lane >> 4;
    const int nt = K >> 6;

    floatx4 acc[4][4];
#pragma unroll
    for (int i = 0; i < 4; ++i)
#pragma unroll
        for (int j = 0; j < 4; ++j) acc[i][j] = (floatx4){0.f, 0.f, 0.f, 0.f};

    for (int t = 0; t < nt; ++t) {
        const int kb = t << 7;
        stage_tile_s(A, rma, a_rows, row0, kb, lds);
        stage_tile_s(B, rmb, b_rows, col0, kb, lds + 16384);
        asm volatile("s_waitcnt vmcnt(0)" ::: "memory");
        __builtin_amdgcn_s_barrier();
#pragma unroll
        for (int ks = 0; ks < 2; ++ks) {
            short8 av[4], bv[4];
#pragma unroll
            for (int mi = 0; mi < 4; ++mi) {
                int row = wrow + mi * 16 + lr;
                int cb = (ks * 64 + kg * 16) ^ ((row & 7) << 4);
                av[mi] = *(const short8*)(lds + row * 128 + cb);
            }
#pragma unroll
            for (int ni = 0; ni < 4; ++ni) {
                int row = wcol + ni * 16 + lr;
                int cb = (ks * 64 + kg * 16) ^ ((row & 7) << 4);
                bv[ni] = *(const short8*)(lds + 16384 + row * 128 + cb);
            }
#pragma unroll
            for (int mi = 0; mi < 4; ++mi)
#pragma unroll
                for (int ni = 0; ni < 4; ++ni)
                    acc[mi][ni] = __builtin_amdgcn_mfma_f32_16x16x32_bf16(av[mi], bv[ni],
                                                                          acc[mi][ni], 0, 0, 0);
        }
        asm volatile("s_waitcnt lgkmcnt(0)" ::: "memory");
        __builtin_amdgcn_s_barrier();
    }
#pragma unroll
    for (int mi = 0; mi < 4; ++mi)
#pragma unroll
        for (int ni = 0; ni < 4; ++ni)
#pragma unroll
            for (int rr = 0; rr < 4; ++rr)
                epi(row0 + wrow + mi * 16 + kg * 4 + rr, col0 + wcol + ni * 16 + lr,
                    acc[mi][ni][rr]);
}

// scores[z][i][j] = q_scaled[i].k[j]  (bf16, cols padded to 256), z = local bnh
__global__ __launch_bounds__(256, 4) void k_qk(const u16* __restrict__ q,
                                               const u16* __restrict__ kvc,
                                               u16* __restrict__ sc, int bn0) {
    __shared__ __align__(128) char lds[32768];
    const int z = blockIdx.z, bnl = z >> 3, h = z & 7;
    const char* A = (const char*)(q + ((size_t)(bn0 + bnl) * CTX) * DMODEL + h * DH);
    const char* B = (const char*)(kvc + ((size_t)bnl * CTX) * (2 * DMODEL) + h * DH);
    u16* out = sc + (size_t)z * CTX * 256;
    gemm_core_s(A, [](int r) { return (size_t)r * (DMODEL * 2); }, CTX, B,
                [](int r) { return (size_t)r * (4 * DMODEL); }, CTX, DH, blockIdx.x * 128,
                blockIdx.y * 128, lds, [&](int r, int c, float v) {
                    if (r < CTX) out[(size_t)r * 256 + c] = f2bf(v);
                });
}

// scores[m][i][j] += q'[m].rel[i][j]  (batched over i; A gathered from q via row map)
__global__ __launch_bounds__(256, 4) void k_pos(const u16* __restrict__ q,
                                                const u16* __restrict__ rel,
                                                u16* __restrict__ sc, int m0) {
    __shared__ __align__(128) char lds[32768];
    const int i = blockIdx.z;
    const char* B = (const char*)(rel + (size_t)i * CTX * DH);
    u16* out = sc + i * 256;
    gemm_core_s((const char*)q,
                [=](int r) {
                    int m = m0 + r;
                    return (size_t)(((m >> 3) * CTX + i) * DMODEL + (m & 7) * DH) * 2;
                },
                AM, B, [](int r) { return (size_t)r * (DH * 2); }, CTX, DH, blockIdx.x * 128,
                blockIdx.y * 128, lds, [&](int r, int c, float v) {
                    if (r < AM) {
                        size_t idx = (size_t)r * (CTX * 256) + c;
                        out[idx] = f2bf(bf2f(out[idx]) + v);
                    }
                });
}

// attn_out[(bn0+z/8)*CTX+i][(z&7)*DH+dh] = P[z][i][:].vT[z][dh][:]  (K=256 padded)
__global__ __launch_bounds__(256, 4) void k_pv(const u16* __restrict__ P,
                                               const u16* __restrict__ vT,
                                               u16* __restrict__ attn, int bn0) {
    __shared__ __align__(128) char lds[32768];
    const int z = blockIdx.z;
    u16* out = attn + ((size_t)(bn0 + (z >> 3)) * CTX) * DMODEL + (z & 7) * DH;
    const char* A = (const char*)(P + (size_t)z * CTX * 256);
    const char* B = (const char*)(vT + (size_t)z * DH * 256);
    gemm_core_s(A, [](int r) { return (size_t)r * 512; }, CTX, B,
                [](int r) { return (size_t)r * 512; }, DH, 256, blockIdx.x * 128, 0, lds,
                [&](int r, int c, float v) {
                    if (r < CTX) out[(size_t)r * DMODEL + c] = f2bf(v);
                });
}

// ---------------- LayerNorm: wave-per-row, 4 rows/block, in-wave reduction ----------------
template <bool OUTF32>
__global__ __launch_bounds__(256) void k_ln(const float* __restrict__ x,
                                            const float* __restrict__ g,
                                            const float* __restrict__ b, void* __restrict__ out) {
    const int wv = threadIdx.x >> 6, lane = threadIdx.x & 63;
    const int row = blockIdx.x * 4 + wv;  // grid = R_TOT/4
    const float4* xr = (const float4*)(x + (size_t)row * DMODEL);
    float4 v[4];
    float s = 0.f, q = 0.f;
#pragma unroll
    for (int i = 0; i < 4; ++i) {
        v[i] = xr[lane + i * 64];
        s += v[i].x + v[i].y + v[i].z + v[i].w;
        q += v[i].x * v[i].x + v[i].y * v[i].y + v[i].z * v[i].z + v[i].w * v[i].w;
    }
#pragma unroll
    for (int off = 32; off > 0; off >>= 1) { s += __shfl_down(s, off); q += __shfl_down(q, off); }
    s = __shfl(s, 0);
    q = __shfl(q, 0);
    const float mu = s * (1.f / DMODEL);
    const float rstd = rsqrtf(q * (1.f / DMODEL) - mu * mu + 1e-5f);
#pragma unroll
    for (int i = 0; i < 4; ++i) {
        const float4 gv = ((const float4*)g)[lane + i * 64];
        const float4 bv = ((const float4*)b)[lane + i * 64];
        float o0 = (v[i].x - mu) * rstd * gv.x + bv.x;
        float o1 = (v[i].y - mu) * rstd * gv.y + bv.y;
        float o2 = (v[i].z - mu) * rstd * gv.z + bv.z;
        float o3 = (v[i].w - mu) * rstd * gv.w + bv.w;
        if (OUTF32) {
            ((float4*)out)[(size_t)row * 256 + lane + i * 64] = make_float4(o0, o1, o2, o3);
        } else {
            ushort4 r4;
            r4.x = f2bf(o0); r4.y = f2bf(o1); r4.z = f2bf(o2); r4.w = f2bf(o3);
            ((ushort4*)out)[(size_t)row * 256 + lane + i * 64] = r4;
        }
    }
}

// softmax over j: wave-per-row, 4 rows/block; in-place bf16; zeroes pad cols [CTX,256)
__global__ __launch_bounds__(256) void k_softmax(u16* __restrict__ sc) {
    const int wv = threadIdx.x >> 6, lane = threadIdx.x & 63;
    const size_t row = (size_t)blockIdx.x * 4 + wv;  // grid = rows/4
    u16* p = sc + row * 256;
    const ushort4 d = ((const ushort4*)p)[lane];  // cols lane*4 .. lane*4+3
    float f[4];
    const u16 dv[4] = {d.x, d.y, d.z, d.w};
#pragma unroll
    for (int e = 0; e < 4; ++e)
        f[e] = (lane * 4 + e < CTX) ? bf2f(dv[e]) : -3.0e38f;
    float m = fmaxf(fmaxf(f[0], f[1]), fmaxf(f[2], f[3]));
#pragma unroll
    for (int off = 32; off > 0; off >>= 1) m = fmaxf(m, __shfl_down(m, off));
    m = __shfl(m, 0);
    float e4[4];
    float s = 0.f;
#pragma unroll
    for (int e = 0; e < 4; ++e) {
        e4[e] = (lane * 4 + e < CTX) ? __expf(f[e] - m) : 0.f;
        s += e4[e];
    }
#pragma unroll
    for (int off = 32; off > 0; off >>= 1) s += __shfl_down(s, off);
    s = __shfl(s, 0);
    const float inv = 1.f / s;
    ushort4 o;
    o.x = f2bf(e4[0] * inv);
    o.y = f2bf(e4[1] * inv);
    o.z = f2bf(e4[2] * inv);
    o.w = f2bf(e4[3] * inv);
    ((ushort4*)p)[lane] = o;
}

// GLU over mid[16000][4096]: a = cols [0,2048), gate = cols [2048,4096); in-place on a
// 2 rows per 256-thread block (half-wave... wave 0-1 row0, wave 2-3 row1 via tid>>7)
__global__ __launch_bounds__(256) void k_glu(u16* __restrict__ mid) {
    const size_t r = (size_t)blockIdx.x * 2 + (threadIdx.x >> 7);
    const int c = (threadIdx.x & 127) * 16;
    const short8 a8a = *(const short8*)(mid + r * 4096 + c);
    const short8 a8b = *(const short8*)(mid + r * 4096 + c + 8);
    const short8 g8a = *(const short8*)(mid + r * 4096 + 2048 + c);
    const short8 g8b = *(const short8*)(mid + r * 4096 + 2048 + c + 8);
    short8 o8a, o8b;
#pragma unroll
    for (int e = 0; e < 8; ++e) {
        float av = bf2f((u16)a8a[e]), gg = bf2f((u16)g8a[e]);
        o8a[e] = (short)f2bf(av * sigmoidf_(gg));
        float av2 = bf2f((u16)a8b[e]), gg2 = bf2f((u16)g8b[e]);
        o8b[e] = (short)f2bf(av2 * sigmoidf_(gg2));
    }
    *(short8*)(mid + r * 4096 + c) = o8a;
    *(short8*)(mid + r * 4096 + c + 8) = o8b;
}

// depthwise conv(K=15,pad=7)+BN(eval)+silu ; in = a-region (ld 4096), out = gate-region
__global__ __launch_bounds__(256) void k_dwconv(const u16* __restrict__ in,
                                                const float* __restrict__ w,
                                                const float* __restrict__ bng,
                                                const float* __restrict__ bnb,
                                                const float* __restrict__ bnm,
                                                const float* __restrict__ bnv,
                                                u16* __restrict__ out) {
    const int b = blockIdx.z, lt = blockIdx.x, cg = blockIdx.y;
    const int c = cg * 256 + threadIdx.x;  // 0..2047
    const int l0 = lt * 16;
    __shared__ u16 s[30][256];
#pragma unroll
    for (int rr = 0; rr < 30; ++rr) {
        int l = l0 + rr - 7;
        u16 v = 0;
        if (l >= 0 && l < 2000) v = in[((size_t)b * 2000 + l) * 4096 + c];
        s[rr][threadIdx.x] = v;
    }
    __syncthreads();
    float wv[15];
#pragma unroll
    for (int k = 0; k < 15; ++k) wv[k] = w[c * 15 + k];
    const float sc = rsqrtf(bnv[c] + 1e-5f) * bng[c];
    const float mean = bnm[c], bb = bnb[c];
#pragma unroll
    for (int l = 0; l < 16; ++l) {
        float acc = 0.f;
#pragma unroll
        for (int k = 0; k < 15; ++k) acc += bf2f(s[l + k][threadIdx.x]) * wv[k];
        float h = (acc - mean) * sc + bb;
        h = h * sigmoidf_(h);
        out[((size_t)b * 2000 + l0 + l) * 4096 + c] = f2bf(h);
    }
}

// weight transpose f32[K,N] -> bf16[N,K]
__global__ __launch_bounds__(256) void k_wt(const float* __restrict__ w, u16* __restrict__ wt,
                                            int K, int N) {
    __shared__ float tile[32][33];
    const int k0 = blockIdx.x * 32, n0 = blockIdx.y * 32;
    const int tx = threadIdx.x & 31, ty = threadIdx.x >> 5;
#pragma unroll
    for (int i = 0; i < 32; i += 8) tile[ty + i][tx] = w[(size_t)(k0 + ty + i) * N + n0 + tx];
    __syncthreads();
#pragma unroll
    for (int i = 0; i < 32; i += 8)
        wt[(size_t)(n0 + ty + i) * K + k0 + tx] = f2bf(tile[tx][ty + i]);
}

// rel_bf16[i][j][dh] = bf16(rel_emb[dist[i][j]][dh]) ; 2 (i,j) pairs per 256-thr block
__global__ __launch_bounds__(256) void k_rel(const float* __restrict__ emb,
                                             const int* __restrict__ dist,
                                             u16* __restrict__ rel) {
    const int pair = blockIdx.x * 2 + (threadIdx.x >> 7);
    const int lane = threadIdx.x & 127;
    const int d = dist[pair];
    rel[(size_t)pair * DH + lane] = f2bf(emb[(size_t)d * DH + lane]);
}

// vT[z][dh][j] = v_chunk[bnl*CTX+j][DMODEL + h*DH + dh], zero-padded j in [CTX,256)
__global__ __launch_bounds__(256) void k_vt(const u16* __restrict__ kvc, u16* __restrict__ vT) {
    __shared__ u16 t_[64 * 130];
    const int z = blockIdx.x, jt = blockIdx.y;
    const int bnl = z >> 3, h = z & 7;
    const int j0 = jt * 64;
    for (int idx = threadIdx.x; idx < 8192; idx += 256) {
        int j = idx >> 7, dh = idx & 127;
        int jj = j0 + j;
        u16 val = 0;
        if (jj < CTX) val = kvc[((size_t)(bnl * CTX + jj)) * (2 * DMODEL) + DMODEL + h * DH + dh];
        t_[j * 130 + dh] = val;
    }
    __syncthreads();
    for (int idx = threadIdx.x; idx < 8192; idx += 256) {
        int dh = idx >> 6, j = idx & 63;
        vT[((size_t)z * DH + dh) * 256 + j0 + j] = t_[j * 130 + dh];
    }
}

__global__ void k_fill(float* o, int n, float v) {
    int i = blockIdx.x * 256 + threadIdx.x;
    if (i < n) o[i] = v;
}

extern "C" void kernel_launch(void* const* d_in, const int* in_sizes, int n_in, void* d_out,
                              int out_size, void* d_ws, size_t ws_size, hipStream_t stream) {
    const float* x_in = (const float*)d_in[0];
    const int* dists = (const int*)d_in[1];
    const float* ff1_ln_g = (const float*)d_in[2];
    const float* ff1_ln_b = (const float*)d_in[3];
    const float* ff1_up_w = (const float*)d_in[4];
    const float* ff1_up_b = (const float*)d_in[5];
    const float* ff1_down_w = (const float*)d_in[6];
    const float* ff1_down_b = (const float*)d_in[7];
    const float* attn_ln_g = (const float*)d_in[8];
    const float* attn_ln_b = (const float*)d_in[9];
    const float* wq = (const float*)d_in[10];
    const float* wkv = (const float*)d_in[11];
    const float* wo = (const float*)d_in[12];
    const float* wo_b = (const float*)d_in[13];
    const float* rel_emb = (const float*)d_in[14];
    const float* conv_ln_g = (const float*)d_in[15];
    const float* conv_ln_b = (const float*)d_in[16];
    const float* conv_up_w = (const float*)d_in[17];
    const float* conv_up_b = (const float*)d_in[18];
    const float* dw_w = (const float*)d_in[19];
    const float* bn_g = (const float*)d_in[20];
    const float* bn_b = (const float*)d_in[21];
    const float* bn_mean = (const float*)d_in[22];
    const float* bn_var = (const float*)d_in[23];
    const float* conv_down_w = (const float*)d_in[24];
    const float* conv_down_b = (const float*)d_in[25];
    const float* ff2_ln_g = (const float*)d_in[26];
    const float* ff2_ln_b = (const float*)d_in[27];
    const float* ff2_up_w = (const float*)d_in[28];
    const float* ff2_up_b = (const float*)d_in[29];
    const float* ff2_down_w = (const float*)d_in[30];
    const float* ff2_down_b = (const float*)d_in[31];
    const float* post_ln_g = (const float*)d_in[32];
    const float* post_ln_b = (const float*)d_in[33];

    char* W = (char*)d_ws;
    size_t off = 0;
    auto alloc = [&](size_t bytes) {
        char* p = W + off;
        off += (bytes + 255) & ~(size_t)255;
        return (u16*)p;
    };
    u16* slot = alloc((size_t)4096 * 1024 * 2);
    u16* ln_buf = alloc((size_t)R_TOT * DMODEL * 2);
    u16* arena = alloc((size_t)R_TOT * DFF * 2);
    u16* mid = arena;
    u16* rel_bf = arena;
    u16* bufA = rel_bf + (size_t)CTX * CTX * DH;
    u16* bufB = bufA + (size_t)AROWS * 2 * DMODEL;
    u16* smid = bufB + (size_t)R_TOT * DMODEL;
    u16* vT = smid + (size_t)AM * CTX * 256;
    float* xs = (float*)d_out;

    if (ws_size < off) {
        k_fill<<<(out_size + 255) / 256, 256, 0, stream>>>((float*)d_out, out_size, 31337.f);
        return;
    }

    auto WT = [&](const float* s, int K, int N) {
        k_wt<<<dim3(K / 32, N / 32), 256, 0, stream>>>(s, slot, K, N);
    };

    const dim3 gUP(128, 32);  // 128^2: M=16000(->128 tiles), N=4096
    const dim3 gSQ(128, 8);   // M=16000, N=1024
    const dim3 gKV(64, 16);   // M=8000,  N=2048

    auto ff_block = [&](const float* lng, const float* lnb, const float* upw, const float* upb,
                        const float* dnw, const float* dnb, const float* resid,
                        const float* xsrc) {
        k_ln<false><<<R_TOT / 4, 256, 0, stream>>>(xsrc, lng, lnb, ln_buf);
        WT(upw, 1024, 4096);
        k_g<1><<<gUP, 256, 0, stream>>>(ln_buf, DMODEL, slot, DMODEL, upb, 1.f, mid, DFF,
                                        nullptr, R_TOT, DFF, DMODEL);
        WT(dnw, 4096, 1024);
        k_g<2><<<gSQ, 256, 0, stream>>>(mid, DFF, slot, DFF, dnb, 0.5f, xs, DMODEL, resid,
                                        R_TOT, DMODEL, DFF);
    };

    // ---- FF1 ----
    ff_block(ff1_ln_g, ff1_ln_b, ff1_up_w, ff1_up_b, ff1_down_w, ff1_down_b, x_in, x_in);

    // ---- Attention ----
    k_ln<false><<<R_TOT / 4, 256, 0, stream>>>(xs, attn_ln_g, attn_ln_b, ln_buf);
    k_rel<<<CTX * CTX / 2, 256, 0, stream>>>(rel_emb, dists, rel_bf);
    WT(wq, 1024, 1024);
    k_g<0><<<gSQ, 256, 0, stream>>>(ln_buf, DMODEL, slot, DMODEL, nullptr, SCALE_Q, bufB,
                                    DMODEL, nullptr, R_TOT, DMODEL, DMODEL);
    WT(wkv, 1024, 2048);
    for (int h = 0; h < 2; ++h) {
        const int bn0 = h * ABN, m0 = bn0 * 8;
        const u16* lnc = ln_buf + (size_t)bn0 * CTX * DMODEL;
        k_g<0><<<gKV, 256, 0, stream>>>(lnc, DMODEL, slot, DMODEL, nullptr, 1.f, bufA,
                                        2 * DMODEL, nullptr, AROWS, 2 * DMODEL, DMODEL);
        k_vt<<<dim3(AM, 4), 256, 0, stream>>>(bufA, vT);
        k_qk<<<dim3(2, 2, AM), 256, 0, stream>>>(bufB, bufA, smid, bn0);
        k_pos<<<dim3(3, 2, CTX), 256, 0, stream>>>(bufB, rel_bf, smid, m0);
        k_softmax<<<AM * CTX / 4, 256, 0, stream>>>(smid);
        k_pv<<<dim3(2, 1, AM), 256, 0, stream>>>(smid, vT, bufB, bn0);
    }
    WT(wo, 1024, 1024);
    k_g<2><<<gSQ, 256, 0, stream>>>(bufB, DMODEL, slot, DMODEL, wo_b, 1.f, xs, DMODEL, xs,
                                    R_TOT, DMODEL, DMODEL);

    // ---- Conv module: up (a|gate) -> GLU in-place -> dwconv a->gate region -> down ----
    k_ln<false><<<R_TOT / 4, 256, 0, stream>>>(xs, conv_ln_g, conv_ln_b, ln_buf);
    WT(conv_up_w, 1024, 4096);
    k_g<0><<<gUP, 256, 0, stream>>>(ln_buf, DMODEL, slot, DMODEL, conv_up_b, 1.f, mid, DFF,
                                    nullptr, R_TOT, DFF, DMODEL);
    k_glu<<<R_TOT / 2, 256, 0, stream>>>(mid);
    k_dwconv<<<dim3(125, 8, 8), 256, 0, stream>>>(mid, dw_w, bn_g, bn_b, bn_mean, bn_var,
                                                  mid + INNER);
    WT(conv_down_w, 2048, 1024);
    k_g<2><<<gSQ, 256, 0, stream>>>(mid + INNER, DFF, slot, INNER, conv_down_b, 1.f, xs,
                                    DMODEL, xs, R_TOT, DMODEL, INNER);

    // ---- FF2 ----
    ff_block(ff2_ln_g, ff2_ln_b, ff2_up_w, ff2_up_b, ff2_down_w, ff2_down_b, xs, xs);

    // ---- final LayerNorm (in-place on d_out) ----
    k_ln<true><<<R_TOT / 4, 256, 0, stream>>>(xs, post_ln_g, post_ln_b, d_out);
}